// Round 15
// baseline (550.594 us; speedup 1.0000x reference)
//
#include <hip/hip_runtime.h>

#define NTOK 16384
#define DM 1024
#define DFF 2048
#define NE 8

typedef unsigned short u16;
typedef __attribute__((ext_vector_type(8))) short bf16x8;
typedef __attribute__((ext_vector_type(4))) float f32x4;

__device__ __forceinline__ u16 f2bf(float f) {
  unsigned u = __float_as_uint(f);
  u += 0x7fff + ((u >> 16) & 1);
  return (u16)(u >> 16);
}

__device__ __forceinline__ void async16(const void* g, void* l) {
  __builtin_amdgcn_global_load_lds(
      (const __attribute__((address_space(1))) unsigned int*)g,
      (__attribute__((address_space(3))) unsigned int*)l, 16, 0, 0);
}

// ---------------- routing ----------------
__global__ void k_count(const int* __restrict__ idx, int* __restrict__ counts) {
  int t = blockIdx.x * 256 + threadIdx.x;
  atomicAdd(&counts[idx[t]], 1);
}

__global__ void k_offsets(int* __restrict__ c) {
  if (threadIdx.x == 0) {
    int acc = 0;
    for (int e = 0; e < NE; e++) { c[8 + e] = acc; c[16 + e] = acc; acc += c[e]; }
  }
}

__global__ void k_scatter(const int* __restrict__ idx, int* __restrict__ cursor,
                          int* __restrict__ tl) {
  int t = blockIdx.x * 256 + threadIdx.x;
  int pos = atomicAdd(&cursor[idx[t]], 1);
  tl[pos] = t;
}

// ---------------- fp32 -> bf16 conversion: x + wgu only ----------------
__global__ void k_cvt_xw(const float* __restrict__ x, const float* __restrict__ wgu,
                         u16* __restrict__ xb, u16* __restrict__ wgub) {
  const size_t N1 = (size_t)NTOK * DM;
  const size_t N2 = (size_t)NE * 2 * DFF * DM;
  const size_t total4 = (N1 + N2) / 4;
  for (size_t q = (size_t)blockIdx.x * 256 + threadIdx.x; q < total4;
       q += (size_t)gridDim.x * 256) {
    size_t i = q * 4;
    const float* s;
    u16* d;
    if (i < N1) { s = x + i; d = xb + i; }
    else { s = wgu + (i - N1); d = wgub + (i - N1); }
    float4 v = *(const float4*)s;
    ushort4 o;
    o.x = f2bf(v.x); o.y = f2bf(v.y); o.z = f2bf(v.z); o.w = f2bf(v.w);
    *(ushort4*)d = o;
  }
}

// ---------------- GEMM1: hidden = silu(x@Wg^T) * (x@Wu^T) ----------------
// Exact r12/r14 form: r6 geometry + barrier diet + serial wd->wdb fold prologue.
__global__ __launch_bounds__(512, 2) void k_gemm1(
    const u16* __restrict__ xb, const u16* __restrict__ wgu,
    u16* __restrict__ hid, const int* __restrict__ tl,
    const int* __restrict__ offs, const int* __restrict__ counts,
    const float* __restrict__ wd, u16* __restrict__ wdb) {
  int wg = blockIdx.x;
  int tid = threadIdx.x;

  // ---- wd fp32 -> bf16 fold (all 1152 blocks participate) ----
  {
    const size_t WD4 = (size_t)NE * DM * DFF / 4;
    for (size_t i = (size_t)wg * 512 + tid; i < WD4; i += (size_t)1152 * 512) {
      float4 v = *(const float4*)(wd + i * 4);
      ushort4 o;
      o.x = f2bf(v.x); o.y = f2bf(v.y); o.z = f2bf(v.z); o.w = f2bf(v.w);
      *(ushort4*)(wdb + i * 4) = o;
    }
  }

  int e = wg & 7;            // expert -> XCD pin
  int r = wg >> 3;           // 0..143
  int bx = r % 9;            // fastest: consecutive blocks share B y-panel
  int by = r / 9;            // 0..15
  int Me = counts[e];
  int m0 = bx * 256;
  if (m0 >= Me) return;
  int n0 = by * 128;
  int oe = offs[e];
  const int* tle = tl + oe;

  int lane = tid & 63;
  int wid = tid >> 6;        // 0..7
  int wm = wid >> 2;         // 0..1
  int wn = wid & 3;          // 0..3

  __shared__ u16 lds[2][2][256 * 64];  // 128 KiB

  int lr = lane >> 3;
  int swz = ((lane & 7) ^ lr) * 8;     // pre-swizzled source slot
  const u16* pA[4];
  const u16* pB[4];
#pragma unroll
  for (int j = 0; j < 4; j++) {
    int c = j * 8 + wid;               // 0..31
    int a = m0 + c * 8 + lr;
    if (a >= Me) a = Me - 1;
    pA[j] = xb + (size_t)tle[a] * DM + swz;
    int b = c * 8 + lr;                // 0..255
    int grow = ((b >> 5) & 1) * DFF + n0 + ((b >> 6) & 3) * 32 + (b & 31);
    pB[j] = wgu + ((size_t)e * 2 * DFF + grow) * DM + swz;
  }

  f32x4 acc[8][4];
#pragma unroll
  for (int m = 0; m < 8; m++)
#pragma unroll
    for (int f = 0; f < 4; f++) acc[m][f] = (f32x4){0.f, 0.f, 0.f, 0.f};

  const int r15 = lane & 15;
  const int hi4 = lane >> 4;
  const int rx = r15 & 7;

#pragma unroll
  for (int j = 0; j < 4; j++) {
    int off = (j * 8 + wid) * 1024;
    async16(pA[j], (char*)&lds[0][0][0] + off);
    async16(pB[j], (char*)&lds[0][1][0] + off);
  }
  asm volatile("s_waitcnt vmcnt(0)" ::: "memory");
  __builtin_amdgcn_s_barrier();
  __builtin_amdgcn_sched_barrier(0);

  int cur = 0;
#pragma unroll 1
  for (int t = 0; t < DM / 64; t++) {
    const char* Ab = (const char*)&lds[cur][0][0];
    const char* Bb = (const char*)&lds[cur][1][0];
    char* LA = (char*)&lds[cur ^ 1][0][0];
    char* LB = (char*)&lds[cur ^ 1][1][0];
    int k1 = (t + 1) * 64;
    bool pf = (t < DM / 64 - 1);
    bf16x8 bfr[4][2];
#pragma unroll
    for (int p = 0; p < 4; p++) {
      if (p == 0) {
#pragma unroll
        for (int f = 0; f < 4; f++)
#pragma unroll
          for (int kk = 0; kk < 2; kk++) {
            int row = wn * 64 + f * 16 + r15;
            bfr[f][kk] = *(const bf16x8*)(Bb + row * 128 + (((kk * 4 + hi4) ^ rx) * 16));
          }
      }
      bf16x8 af[2][2];
#pragma unroll
      for (int i = 0; i < 2; i++)
#pragma unroll
        for (int kk = 0; kk < 2; kk++) {
          int row = wm * 128 + (2 * p + i) * 16 + r15;
          af[i][kk] = *(const bf16x8*)(Ab + row * 128 + (((kk * 4 + hi4) ^ rx) * 16));
        }
      if (pf && p < 2) {
#pragma unroll
        for (int j = 0; j < 2; j++) {
          int jj = p * 2 + j;
          int off = (jj * 8 + wid) * 1024;
          async16(pA[jj] + k1, LA + off);
          async16(pB[jj] + k1, LB + off);
        }
      }
      __builtin_amdgcn_sched_barrier(0);
      __builtin_amdgcn_s_setprio(1);
#pragma unroll
      for (int kk = 0; kk < 2; kk++)
#pragma unroll
        for (int i = 0; i < 2; i++)
#pragma unroll
          for (int f = 0; f < 4; f++)
            acc[2 * p + i][f] = __builtin_amdgcn_mfma_f32_16x16x32_bf16(
                af[i][kk], bfr[f][kk], acc[2 * p + i][f], 0, 0, 0);
      __builtin_amdgcn_s_setprio(0);
      __builtin_amdgcn_sched_barrier(0);
    }
    asm volatile("s_waitcnt vmcnt(0)" ::: "memory");
    __builtin_amdgcn_s_barrier();
    __builtin_amdgcn_sched_barrier(0);
    cur ^= 1;
  }

  int colb = n0 + wn * 32 + r15;
#pragma unroll
  for (int m = 0; m < 8; m++) {
#pragma unroll
    for (int rr = 0; rr < 4; rr++) {
      int gm = m0 + wm * 128 + m * 16 + hi4 * 4 + rr;
      if (gm < Me) {
        size_t rowp = (size_t)(oe + gm) * DFF;
#pragma unroll
        for (int f = 0; f < 2; f++) {
          float g = acc[m][f][rr];
          float u = acc[m][f + 2][rr];
          float s = g / (1.0f + __expf(-g));
          hid[rowp + colb + f * 16] = f2bf(s * u);
        }
      }
    }
  }
}

// ---------------- GEMM2: out[tok] += hidden[:,Ks] @ Wd[:,Ks]^T --------------
// K-SPLIT quantum halving: each block does 256x256 output over K half
// s*1024..(s+1)*1024 (16 tiles, ~48us). Grid 9bx x 2s x 4by x 8e = 576 blocks
// -> ~2.15 rounds of half-cost blocks (vs 2 rounds of full blocks).
// Combine via fp32 atomicAdd onto zeroed out (2 addends/loc, commutative ->
// deterministic). r12 schedule (4 phases x 16 MFMA, barrier diet) unchanged.
__global__ __launch_bounds__(512, 2) void k_gemm2(
    const u16* __restrict__ hid, const u16* __restrict__ wd,
    float* __restrict__ out, const int* __restrict__ tl,
    const int* __restrict__ offs, const int* __restrict__ counts) {
  int wg = blockIdx.x;
  int e = wg & 7;
  int r = wg >> 3;           // 0..71
  int by = r / 18;           // 0..3
  int q2 = r % 18;
  int bx = q2 >> 1;          // 0..8
  int s = q2 & 1;            // K half
  int Me = counts[e];
  int m0 = bx * 256;
  if (m0 >= Me) return;
  int n0 = by * 256;
  int kbase = s * (DFF / 2); // 0 or 1024
  int oe = offs[e];
  const int* tle = tl + oe;

  int tid = threadIdx.x;
  int lane = tid & 63;
  int wid = tid >> 6;
  int wm = wid >> 2;         // 0..1
  int wn = wid & 3;          // 0..3

  __shared__ u16 lds[2][2][256 * 64];  // 128 KiB

  int lr = lane >> 3;
  int swz = ((lane & 7) ^ lr) * 8;
  const u16* pA[4];
  const u16* pB[4];
#pragma unroll
  for (int j = 0; j < 4; j++) {
    int c = j * 8 + wid;               // 0..31
    int a = m0 + c * 8 + lr;
    if (a >= Me) a = Me - 1;
    pA[j] = hid + (size_t)(oe + a) * DFF + kbase + swz;
    pB[j] = wd + ((size_t)e * DM + n0 + c * 8 + lr) * DFF + kbase + swz;
  }

  f32x4 acc[8][4];
#pragma unroll
  for (int m = 0; m < 8; m++)
#pragma unroll
    for (int f = 0; f < 4; f++) acc[m][f] = (f32x4){0.f, 0.f, 0.f, 0.f};

  const int r15 = lane & 15;
  const int hi4 = lane >> 4;
  const int rx = r15 & 7;

#pragma unroll
  for (int j = 0; j < 4; j++) {
    int off = (j * 8 + wid) * 1024;
    async16(pA[j], (char*)&lds[0][0][0] + off);
    async16(pB[j], (char*)&lds[0][1][0] + off);
  }
  asm volatile("s_waitcnt vmcnt(0)" ::: "memory");
  __builtin_amdgcn_s_barrier();
  __builtin_amdgcn_sched_barrier(0);

  const int NT = DFF / 2 / 64;  // 16 tiles per K half
  int cur = 0;
#pragma unroll 1
  for (int t = 0; t < NT; t++) {
    const char* Ab = (const char*)&lds[cur][0][0];
    const char* Bb = (const char*)&lds[cur][1][0];
    char* LA = (char*)&lds[cur ^ 1][0][0];
    char* LB = (char*)&lds[cur ^ 1][1][0];
    int k1 = (t + 1) * 64;
    bool pf = (t < NT - 1);
    bf16x8 bfr[4][2];
#pragma unroll
    for (int p = 0; p < 4; p++) {
      if (p == 0) {
#pragma unroll
        for (int f = 0; f < 4; f++)
#pragma unroll
          for (int kk = 0; kk < 2; kk++) {
            int row = wn * 64 + f * 16 + r15;
            bfr[f][kk] = *(const bf16x8*)(Bb + row * 128 + (((kk * 4 + hi4) ^ rx) * 16));
          }
      }
      bf16x8 af[2][2];
#pragma unroll
      for (int i = 0; i < 2; i++)
#pragma unroll
        for (int kk = 0; kk < 2; kk++) {
          int row = wm * 128 + (2 * p + i) * 16 + r15;
          af[i][kk] = *(const bf16x8*)(Ab + row * 128 + (((kk * 4 + hi4) ^ rx) * 16));
        }
      if (pf && p < 2) {
#pragma unroll
        for (int j = 0; j < 2; j++) {
          int jj = p * 2 + j;
          int off = (jj * 8 + wid) * 1024;
          async16(pA[jj] + k1, LA + off);
          async16(pB[jj] + k1, LB + off);
        }
      }
      __builtin_amdgcn_sched_barrier(0);
      __builtin_amdgcn_s_setprio(1);
#pragma unroll
      for (int kk = 0; kk < 2; kk++)
#pragma unroll
        for (int i = 0; i < 2; i++)
#pragma unroll
          for (int f = 0; f < 4; f++)
            acc[2 * p + i][f] = __builtin_amdgcn_mfma_f32_16x16x32_bf16(
                af[i][kk], bfr[f][kk], acc[2 * p + i][f], 0, 0, 0);
      __builtin_amdgcn_s_setprio(0);
      __builtin_amdgcn_sched_barrier(0);
    }
    asm volatile("s_waitcnt vmcnt(0)" ::: "memory");
    __builtin_amdgcn_s_barrier();
    __builtin_amdgcn_sched_barrier(0);
    cur ^= 1;
  }

  int colb = n0 + wn * 64 + r15;
#pragma unroll
  for (int m = 0; m < 8; m++) {
#pragma unroll
    for (int rr = 0; rr < 4; rr++) {
      int gm = m0 + wm * 128 + m * 16 + hi4 * 4 + rr;
      if (gm < Me) {
        int tk = tle[gm];
#pragma unroll
        for (int f = 0; f < 4; f++)
          atomicAdd(&out[(size_t)tk * DM + colb + f * 16], acc[m][f][rr]);
      }
    }
  }
}

extern "C" void kernel_launch(void* const* d_in, const int* in_sizes, int n_in,
                              void* d_out, int out_size, void* d_ws, size_t ws_size,
                              hipStream_t stream) {
  const float* x   = (const float*)d_in[0];
  const int* eidx  = (const int*)d_in[1];
  const float* wgu = (const float*)d_in[2];
  const float* wd  = (const float*)d_in[3];
  float* out = (float*)d_out;
  char* ws = (char*)d_ws;

  int* ctrl = (int*)ws;                          // counts[8], offs[8], cursor[8]
  int* toklist = (int*)(ws + 256);               // 16384 ints
  u16* xb   = (u16*)(ws + 65792);                // 32 MB
  u16* wgub = (u16*)(ws + 65792 + 33554432ull);  // 64 MB
  u16* wdb  = (u16*)(ws + 65792 + 33554432ull + 67108864ull);   // 32 MB
  u16* hid  = (u16*)(ws + 65792 + 33554432ull + 67108864ull + 33554432ull);  // 64 MB

  // zero out for the K-split atomic accumulation in k_gemm2
  hipMemsetAsync(out, 0, (size_t)NTOK * DM * sizeof(float), stream);

  hipMemsetAsync(ws, 0, 256, stream);
  k_count<<<NTOK / 256, 256, 0, stream>>>(eidx, ctrl);
  k_offsets<<<1, 64, 0, stream>>>(ctrl);
  k_scatter<<<NTOK / 256, 256, 0, stream>>>(eidx, ctrl + 16, toklist);

  k_cvt_xw<<<2048, 256, 0, stream>>>(x, wgu, xb, wgub);

  // counts ~2048 +- 42 (seed-fixed). g1: 9 M-blocks of 256 (2304 = 6 sigma).
  k_gemm1<<<9 * 16 * NE, 512, 0, stream>>>(xb, wgub, hid, toklist, ctrl + 8, ctrl, wd, wdb);
  // g2: K-split (s in {0,1}), 576 half-cost blocks, atomicAdd combine.
  k_gemm2<<<9 * 2 * 4 * NE, 512, 0, stream>>>(hid, wdb, out, toklist, ctrl + 8, ctrl);
}

// Round 16
// 476.829 us; speedup vs baseline: 1.1547x; 1.1547x over previous
//
#include <hip/hip_runtime.h>

#define NTOK 16384
#define DM 1024
#define DFF 2048
#define NE 8

typedef unsigned short u16;
typedef __attribute__((ext_vector_type(8))) short bf16x8;
typedef __attribute__((ext_vector_type(4))) float f32x4;

__device__ __forceinline__ u16 f2bf(float f) {
  unsigned u = __float_as_uint(f);
  u += 0x7fff + ((u >> 16) & 1);
  return (u16)(u >> 16);
}

__device__ __forceinline__ void async16(const void* g, void* l) {
  __builtin_amdgcn_global_load_lds(
      (const __attribute__((address_space(1))) unsigned int*)g,
      (__attribute__((address_space(3))) unsigned int*)l, 16, 0, 0);
}

// ---------------- routing ----------------
__global__ void k_count(const int* __restrict__ idx, int* __restrict__ counts) {
  int t = blockIdx.x * 256 + threadIdx.x;
  atomicAdd(&counts[idx[t]], 1);
}

__global__ void k_offsets(int* __restrict__ c) {
  if (threadIdx.x == 0) {
    int acc = 0;
    for (int e = 0; e < NE; e++) { c[8 + e] = acc; c[16 + e] = acc; acc += c[e]; }
  }
}

__global__ void k_scatter(const int* __restrict__ idx, int* __restrict__ cursor,
                          int* __restrict__ tl) {
  int t = blockIdx.x * 256 + threadIdx.x;
  int pos = atomicAdd(&cursor[idx[t]], 1);
  tl[pos] = t;
}

// ---------------- fp32 -> bf16 conversion: x + wgu only ----------------
__global__ void k_cvt_xw(const float* __restrict__ x, const float* __restrict__ wgu,
                         u16* __restrict__ xb, u16* __restrict__ wgub) {
  const size_t N1 = (size_t)NTOK * DM;
  const size_t N2 = (size_t)NE * 2 * DFF * DM;
  const size_t total4 = (N1 + N2) / 4;
  for (size_t q = (size_t)blockIdx.x * 256 + threadIdx.x; q < total4;
       q += (size_t)gridDim.x * 256) {
    size_t i = q * 4;
    const float* s;
    u16* d;
    if (i < N1) { s = x + i; d = xb + i; }
    else { s = wgu + (i - N1); d = wgub + (i - N1); }
    float4 v = *(const float4*)s;
    ushort4 o;
    o.x = f2bf(v.x); o.y = f2bf(v.y); o.z = f2bf(v.z); o.w = f2bf(v.w);
    *(ushort4*)d = o;
  }
}

// ---------------- GEMM1: hidden = silu(x@Wg^T) * (x@Wu^T) ----------------
// Exact r12/r14 form: r6 geometry + barrier diet + serial wd->wdb fold prologue.
__global__ __launch_bounds__(512, 2) void k_gemm1(
    const u16* __restrict__ xb, const u16* __restrict__ wgu,
    u16* __restrict__ hid, const int* __restrict__ tl,
    const int* __restrict__ offs, const int* __restrict__ counts,
    const float* __restrict__ wd, u16* __restrict__ wdb) {
  int wg = blockIdx.x;
  int tid = threadIdx.x;

  // ---- wd fp32 -> bf16 fold (all 1152 blocks participate) ----
  {
    const size_t WD4 = (size_t)NE * DM * DFF / 4;
    for (size_t i = (size_t)wg * 512 + tid; i < WD4; i += (size_t)1152 * 512) {
      float4 v = *(const float4*)(wd + i * 4);
      ushort4 o;
      o.x = f2bf(v.x); o.y = f2bf(v.y); o.z = f2bf(v.z); o.w = f2bf(v.w);
      *(ushort4*)(wdb + i * 4) = o;
    }
  }

  int e = wg & 7;            // expert -> XCD pin
  int r = wg >> 3;           // 0..143
  int bx = r % 9;            // fastest: consecutive blocks share B y-panel
  int by = r / 9;            // 0..15
  int Me = counts[e];
  int m0 = bx * 256;
  if (m0 >= Me) return;
  int n0 = by * 128;
  int oe = offs[e];
  const int* tle = tl + oe;

  int lane = tid & 63;
  int wid = tid >> 6;        // 0..7
  int wm = wid >> 2;         // 0..1
  int wn = wid & 3;          // 0..3

  __shared__ u16 lds[2][2][256 * 64];  // 128 KiB

  int lr = lane >> 3;
  int swz = ((lane & 7) ^ lr) * 8;     // pre-swizzled source slot
  const u16* pA[4];
  const u16* pB[4];
#pragma unroll
  for (int j = 0; j < 4; j++) {
    int c = j * 8 + wid;               // 0..31
    int a = m0 + c * 8 + lr;
    if (a >= Me) a = Me - 1;
    pA[j] = xb + (size_t)tle[a] * DM + swz;
    int b = c * 8 + lr;                // 0..255
    int grow = ((b >> 5) & 1) * DFF + n0 + ((b >> 6) & 3) * 32 + (b & 31);
    pB[j] = wgu + ((size_t)e * 2 * DFF + grow) * DM + swz;
  }

  f32x4 acc[8][4];
#pragma unroll
  for (int m = 0; m < 8; m++)
#pragma unroll
    for (int f = 0; f < 4; f++) acc[m][f] = (f32x4){0.f, 0.f, 0.f, 0.f};

  const int r15 = lane & 15;
  const int hi4 = lane >> 4;
  const int rx = r15 & 7;

#pragma unroll
  for (int j = 0; j < 4; j++) {
    int off = (j * 8 + wid) * 1024;
    async16(pA[j], (char*)&lds[0][0][0] + off);
    async16(pB[j], (char*)&lds[0][1][0] + off);
  }
  asm volatile("s_waitcnt vmcnt(0)" ::: "memory");
  __builtin_amdgcn_s_barrier();
  __builtin_amdgcn_sched_barrier(0);

  int cur = 0;
#pragma unroll 1
  for (int t = 0; t < DM / 64; t++) {
    const char* Ab = (const char*)&lds[cur][0][0];
    const char* Bb = (const char*)&lds[cur][1][0];
    char* LA = (char*)&lds[cur ^ 1][0][0];
    char* LB = (char*)&lds[cur ^ 1][1][0];
    int k1 = (t + 1) * 64;
    bool pf = (t < DM / 64 - 1);
    bf16x8 bfr[4][2];
#pragma unroll
    for (int p = 0; p < 4; p++) {
      if (p == 0) {
#pragma unroll
        for (int f = 0; f < 4; f++)
#pragma unroll
          for (int kk = 0; kk < 2; kk++) {
            int row = wn * 64 + f * 16 + r15;
            bfr[f][kk] = *(const bf16x8*)(Bb + row * 128 + (((kk * 4 + hi4) ^ rx) * 16));
          }
      }
      bf16x8 af[2][2];
#pragma unroll
      for (int i = 0; i < 2; i++)
#pragma unroll
        for (int kk = 0; kk < 2; kk++) {
          int row = wm * 128 + (2 * p + i) * 16 + r15;
          af[i][kk] = *(const bf16x8*)(Ab + row * 128 + (((kk * 4 + hi4) ^ rx) * 16));
        }
      if (pf && p < 2) {
#pragma unroll
        for (int j = 0; j < 2; j++) {
          int jj = p * 2 + j;
          int off = (jj * 8 + wid) * 1024;
          async16(pA[jj] + k1, LA + off);
          async16(pB[jj] + k1, LB + off);
        }
      }
      __builtin_amdgcn_sched_barrier(0);
      __builtin_amdgcn_s_setprio(1);
#pragma unroll
      for (int kk = 0; kk < 2; kk++)
#pragma unroll
        for (int i = 0; i < 2; i++)
#pragma unroll
          for (int f = 0; f < 4; f++)
            acc[2 * p + i][f] = __builtin_amdgcn_mfma_f32_16x16x32_bf16(
                af[i][kk], bfr[f][kk], acc[2 * p + i][f], 0, 0, 0);
      __builtin_amdgcn_s_setprio(0);
      __builtin_amdgcn_sched_barrier(0);
    }
    asm volatile("s_waitcnt vmcnt(0)" ::: "memory");
    __builtin_amdgcn_s_barrier();
    __builtin_amdgcn_sched_barrier(0);
    cur ^= 1;
  }

  int colb = n0 + wn * 32 + r15;
#pragma unroll
  for (int m = 0; m < 8; m++) {
#pragma unroll
    for (int rr = 0; rr < 4; rr++) {
      int gm = m0 + wm * 128 + m * 16 + hi4 * 4 + rr;
      if (gm < Me) {
        size_t rowp = (size_t)(oe + gm) * DFF;
#pragma unroll
        for (int f = 0; f < 2; f++) {
          float g = acc[m][f][rr];
          float u = acc[m][f + 2][rr];
          float s = g / (1.0f + __expf(-g));
          hid[rowp + colb + f * 16] = f2bf(s * u);
        }
      }
    }
  }
}

// ---------------- GEMM2: merged main + overflow in ONE dispatch -------------
// wg < 256 : main path, r14 geometry (BM=256, BN=256, rows < 2048, 1 round).
// wg >= 256: overflow path (BM=64, rows 2048..2303), ~16 active thin blocks
// that BACKFILL CUs while the main round runs (this was serial in r14).
__global__ __launch_bounds__(512, 2) void k_gemm2(
    const u16* __restrict__ hid, const u16* __restrict__ wd,
    float* __restrict__ out, const int* __restrict__ tl,
    const int* __restrict__ offs, const int* __restrict__ counts) {
  __shared__ u16 lds[2][2][256 * 64];  // 128 KiB, shared by both paths
  int wg = blockIdx.x;
  int tid = threadIdx.x;
  int lane = tid & 63;
  int wid = tid >> 6;
  const int r15 = lane & 15;
  const int hi4 = lane >> 4;
  const int rx = r15 & 7;
  int lr = lane >> 3;
  int swz = ((lane & 7) ^ lr) * 8;

  if (wg < 256) {
    // ================= main path =================
    int e = wg & 7;
    int r = wg >> 3;           // 0..31
    int bx = r & 7;            // 0..7
    int by = r >> 3;           // 0..3
    int Me = counts[e];
    int m0 = bx * 256;
    if (m0 >= Me) return;
    int n0 = by * 256;
    int oe = offs[e];
    const int* tle = tl + oe;
    int wm = wid >> 2;         // 0..1
    int wn = wid & 3;          // 0..3

    const u16* pA[4];
    const u16* pB[4];
#pragma unroll
    for (int j = 0; j < 4; j++) {
      int c = j * 8 + wid;               // 0..31
      int a = m0 + c * 8 + lr;
      if (a >= Me) a = Me - 1;
      pA[j] = hid + (size_t)(oe + a) * DFF + swz;
      pB[j] = wd + ((size_t)e * DM + n0 + c * 8 + lr) * DFF + swz;
    }

    f32x4 acc[8][4];
#pragma unroll
    for (int m = 0; m < 8; m++)
#pragma unroll
      for (int f = 0; f < 4; f++) acc[m][f] = (f32x4){0.f, 0.f, 0.f, 0.f};

#pragma unroll
    for (int j = 0; j < 4; j++) {
      int off = (j * 8 + wid) * 1024;
      async16(pA[j], (char*)&lds[0][0][0] + off);
      async16(pB[j], (char*)&lds[0][1][0] + off);
    }
    asm volatile("s_waitcnt vmcnt(0)" ::: "memory");
    __builtin_amdgcn_s_barrier();
    __builtin_amdgcn_sched_barrier(0);

    int cur = 0;
#pragma unroll 1
    for (int t = 0; t < DFF / 64; t++) {
      const char* Ab = (const char*)&lds[cur][0][0];
      const char* Bb = (const char*)&lds[cur][1][0];
      char* LA = (char*)&lds[cur ^ 1][0][0];
      char* LB = (char*)&lds[cur ^ 1][1][0];
      int k1 = (t + 1) * 64;
      bool pf = (t < DFF / 64 - 1);
      bf16x8 bfr[4][2];
#pragma unroll
      for (int p = 0; p < 4; p++) {
        if (p == 0) {
#pragma unroll
          for (int f = 0; f < 4; f++)
#pragma unroll
            for (int kk = 0; kk < 2; kk++) {
              int row = wn * 64 + f * 16 + r15;
              bfr[f][kk] = *(const bf16x8*)(Bb + row * 128 + (((kk * 4 + hi4) ^ rx) * 16));
            }
        }
        bf16x8 af[2][2];
#pragma unroll
        for (int i = 0; i < 2; i++)
#pragma unroll
          for (int kk = 0; kk < 2; kk++) {
            int row = wm * 128 + (2 * p + i) * 16 + r15;
            af[i][kk] = *(const bf16x8*)(Ab + row * 128 + (((kk * 4 + hi4) ^ rx) * 16));
          }
        if (pf && p < 2) {
#pragma unroll
          for (int j = 0; j < 2; j++) {
            int jj = p * 2 + j;
            int off = (jj * 8 + wid) * 1024;
            async16(pA[jj] + k1, LA + off);
            async16(pB[jj] + k1, LB + off);
          }
        }
        __builtin_amdgcn_sched_barrier(0);
        __builtin_amdgcn_s_setprio(1);
#pragma unroll
        for (int kk = 0; kk < 2; kk++)
#pragma unroll
          for (int i = 0; i < 2; i++)
#pragma unroll
            for (int f = 0; f < 4; f++)
              acc[2 * p + i][f] = __builtin_amdgcn_mfma_f32_16x16x32_bf16(
                  af[i][kk], bfr[f][kk], acc[2 * p + i][f], 0, 0, 0);
        __builtin_amdgcn_s_setprio(0);
        __builtin_amdgcn_sched_barrier(0);
      }
      asm volatile("s_waitcnt vmcnt(0)" ::: "memory");
      __builtin_amdgcn_s_barrier();
      __builtin_amdgcn_sched_barrier(0);
      cur ^= 1;
    }

    int colb = n0 + wn * 64 + r15;
#pragma unroll
    for (int m = 0; m < 8; m++) {
#pragma unroll
      for (int rr = 0; rr < 4; rr++) {
        int gm = m0 + wm * 128 + m * 16 + hi4 * 4 + rr;
        if (gm < Me) {
          int tk = tle[gm];
#pragma unroll
          for (int f = 0; f < 4; f++)
            out[(size_t)tk * DM + colb + f * 16] = acc[m][f][rr];
        }
      }
    }
  } else {
    // ================= overflow path: rows [2048, 2304), BM=64 =============
    int w = wg - 256;          // 0..127
    int e = w & 7;
    int r = w >> 3;            // 0..15
    int bx = r & 3;            // 0..3
    int by = r >> 2;           // 0..3
    int Me = counts[e];
    int m0 = 2048 + bx * 64;
    if (m0 >= Me) return;
    int n0 = by * 256;
    int oe = offs[e];
    const int* tle = tl + oe;
    int wm = wid >> 2;         // 0..1
    int wn = wid & 3;          // 0..3

    // carve ovf buffers from the shared 128 KiB block (u16 offsets)
    u16* base = &lds[0][0][0];
    char* bufA[2] = {(char*)base, (char*)base + 8192};                 // 8 KB each
    char* bufB[2] = {(char*)(base + 16384), (char*)(base + 16384) + 32768};  // 32 KB each

    const u16* pAo;
    const u16* pB[4];
    {
      int a = m0 + wid * 8 + lr;
      if (a >= Me) a = Me - 1;
      pAo = hid + (size_t)(oe + a) * DFF + swz;
    }
#pragma unroll
    for (int j = 0; j < 4; j++) {
      int c = j * 8 + wid;               // 0..31
      pB[j] = wd + ((size_t)e * DM + n0 + c * 8 + lr) * DFF + swz;
    }

    f32x4 acc[2][4];
#pragma unroll
    for (int m = 0; m < 2; m++)
#pragma unroll
      for (int f = 0; f < 4; f++) acc[m][f] = (f32x4){0.f, 0.f, 0.f, 0.f};

    async16(pAo, bufA[0] + wid * 1024);
#pragma unroll
    for (int j = 0; j < 4; j++)
      async16(pB[j], bufB[0] + (j * 8 + wid) * 1024);
    asm volatile("s_waitcnt vmcnt(0)" ::: "memory");
    __builtin_amdgcn_s_barrier();
    __builtin_amdgcn_sched_barrier(0);

    int cur = 0;
#pragma unroll 1
    for (int t = 0; t < DFF / 64; t++) {
      const char* Ab = bufA[cur];
      const char* Bb = bufB[cur];
      char* LA = bufA[cur ^ 1];
      char* LB = bufB[cur ^ 1];
      int k1 = (t + 1) * 64;
      bool pf = (t < DFF / 64 - 1);
#pragma unroll
      for (int kk = 0; kk < 2; kk++) {
        bf16x8 bfr[4], af[2];
#pragma unroll
        for (int f = 0; f < 4; f++) {
          int row = wn * 64 + f * 16 + r15;
          bfr[f] = *(const bf16x8*)(Bb + row * 128 + (((kk * 4 + hi4) ^ rx) * 16));
        }
#pragma unroll
        for (int i = 0; i < 2; i++) {
          int row = wm * 32 + i * 16 + r15;
          af[i] = *(const bf16x8*)(Ab + row * 128 + (((kk * 4 + hi4) ^ rx) * 16));
        }
        if (pf) {
          if (kk == 0) {
            async16(pAo + k1, LA + wid * 1024);
#pragma unroll
            for (int j = 0; j < 2; j++)
              async16(pB[j] + k1, LB + (j * 8 + wid) * 1024);
          } else {
#pragma unroll
            for (int j = 2; j < 4; j++)
              async16(pB[j] + k1, LB + (j * 8 + wid) * 1024);
          }
        }
        __builtin_amdgcn_sched_barrier(0);
        __builtin_amdgcn_s_setprio(1);
#pragma unroll
        for (int i = 0; i < 2; i++)
#pragma unroll
          for (int f = 0; f < 4; f++)
            acc[i][f] = __builtin_amdgcn_mfma_f32_16x16x32_bf16(af[i], bfr[f], acc[i][f], 0, 0, 0);
        __builtin_amdgcn_s_setprio(0);
        __builtin_amdgcn_sched_barrier(0);
      }
      asm volatile("s_waitcnt vmcnt(0)" ::: "memory");
      __builtin_amdgcn_s_barrier();
      __builtin_amdgcn_sched_barrier(0);
      cur ^= 1;
    }

    int colb = n0 + wn * 64 + r15;
#pragma unroll
    for (int m = 0; m < 2; m++) {
#pragma unroll
      for (int rr = 0; rr < 4; rr++) {
        int gm = m0 + wm * 32 + m * 16 + hi4 * 4 + rr;
        if (gm < Me) {
          int tk = tle[gm];
#pragma unroll
          for (int f = 0; f < 4; f++)
            out[(size_t)tk * DM + colb + f * 16] = acc[m][f][rr];
        }
      }
    }
  }
}

extern "C" void kernel_launch(void* const* d_in, const int* in_sizes, int n_in,
                              void* d_out, int out_size, void* d_ws, size_t ws_size,
                              hipStream_t stream) {
  const float* x   = (const float*)d_in[0];
  const int* eidx  = (const int*)d_in[1];
  const float* wgu = (const float*)d_in[2];
  const float* wd  = (const float*)d_in[3];
  float* out = (float*)d_out;
  char* ws = (char*)d_ws;

  int* ctrl = (int*)ws;                          // counts[8], offs[8], cursor[8]
  int* toklist = (int*)(ws + 256);               // 16384 ints
  u16* xb   = (u16*)(ws + 65792);                // 32 MB
  u16* wgub = (u16*)(ws + 65792 + 33554432ull);  // 64 MB
  u16* wdb  = (u16*)(ws + 65792 + 33554432ull + 67108864ull);   // 32 MB
  u16* hid  = (u16*)(ws + 65792 + 33554432ull + 67108864ull + 33554432ull);  // 64 MB

  hipMemsetAsync(ws, 0, 256, stream);
  k_count<<<NTOK / 256, 256, 0, stream>>>(eidx, ctrl);
  k_offsets<<<1, 64, 0, stream>>>(ctrl);
  k_scatter<<<NTOK / 256, 256, 0, stream>>>(eidx, ctrl + 16, toklist);

  k_cvt_xw<<<2048, 256, 0, stream>>>(x, wgu, xb, wgub);

  // counts ~2048 +- 42 (seed-fixed). g1: 9 M-blocks of 256 (2304 = 6 sigma).
  k_gemm1<<<9 * 16 * NE, 512, 0, stream>>>(xb, wgub, hid, toklist, ctrl + 8, ctrl, wd, wdb);
  // g2: ONE dispatch, 256 main blocks (rows < 2048) + 128 overflow blocks
  // (rows 2048..2303) that backfill CUs during the main round.
  k_gemm2<<<384, 512, 0, stream>>>(hid, wdb, out, toklist, ctrl + 8, ctrl);
}

// Round 17
// 466.103 us; speedup vs baseline: 1.1813x; 1.0230x over previous
//
#include <hip/hip_runtime.h>

#define NTOK 16384
#define DM 1024
#define DFF 2048
#define NE 8

typedef unsigned short u16;
typedef __attribute__((ext_vector_type(8))) short bf16x8;
typedef __attribute__((ext_vector_type(4))) float f32x4;

__device__ __forceinline__ u16 f2bf(float f) {
  unsigned u = __float_as_uint(f);
  u += 0x7fff + ((u >> 16) & 1);
  return (u16)(u >> 16);
}

__device__ __forceinline__ void async16(const void* g, void* l) {
  __builtin_amdgcn_global_load_lds(
      (const __attribute__((address_space(1))) unsigned int*)g,
      (__attribute__((address_space(3))) unsigned int*)l, 16, 0, 0);
}

// ---------------- routing ----------------
__global__ void k_count(const int* __restrict__ idx, int* __restrict__ counts) {
  int t = blockIdx.x * 256 + threadIdx.x;
  atomicAdd(&counts[idx[t]], 1);
}

__global__ void k_offsets(int* __restrict__ c) {
  if (threadIdx.x == 0) {
    int acc = 0;
    for (int e = 0; e < NE; e++) { c[8 + e] = acc; c[16 + e] = acc; acc += c[e]; }
  }
}

__global__ void k_scatter(const int* __restrict__ idx, int* __restrict__ cursor,
                          int* __restrict__ tl) {
  int t = blockIdx.x * 256 + threadIdx.x;
  int pos = atomicAdd(&cursor[idx[t]], 1);
  tl[pos] = t;
}

// ---------------- fp32 -> bf16 conversion: x + wgu only ----------------
__global__ void k_cvt_xw(const float* __restrict__ x, const float* __restrict__ wgu,
                         u16* __restrict__ xb, u16* __restrict__ wgub) {
  const size_t N1 = (size_t)NTOK * DM;
  const size_t N2 = (size_t)NE * 2 * DFF * DM;
  const size_t total4 = (N1 + N2) / 4;
  for (size_t q = (size_t)blockIdx.x * 256 + threadIdx.x; q < total4;
       q += (size_t)gridDim.x * 256) {
    size_t i = q * 4;
    const float* s;
    u16* d;
    if (i < N1) { s = x + i; d = xb + i; }
    else { s = wgu + (i - N1); d = wgub + (i - N1); }
    float4 v = *(const float4*)s;
    ushort4 o;
    o.x = f2bf(v.x); o.y = f2bf(v.y); o.z = f2bf(v.z); o.w = f2bf(v.w);
    *(ushort4*)d = o;
  }
}

// ---------------- GEMM1: hidden = silu(x@Wg^T) * (x@Wu^T) ----------------
// r6 geometry + barrier diet + serial wd->wdb fold prologue (r12 form).
__global__ __launch_bounds__(512, 2) void k_gemm1(
    const u16* __restrict__ xb, const u16* __restrict__ wgu,
    u16* __restrict__ hid, const int* __restrict__ tl,
    const int* __restrict__ offs, const int* __restrict__ counts,
    const float* __restrict__ wd, u16* __restrict__ wdb) {
  int wg = blockIdx.x;
  int tid = threadIdx.x;

  // ---- wd fp32 -> bf16 fold (all 1152 blocks participate) ----
  {
    const size_t WD4 = (size_t)NE * DM * DFF / 4;
    for (size_t i = (size_t)wg * 512 + tid; i < WD4; i += (size_t)1152 * 512) {
      float4 v = *(const float4*)(wd + i * 4);
      ushort4 o;
      o.x = f2bf(v.x); o.y = f2bf(v.y); o.z = f2bf(v.z); o.w = f2bf(v.w);
      *(ushort4*)(wdb + i * 4) = o;
    }
  }

  int e = wg & 7;            // expert -> XCD pin
  int r = wg >> 3;           // 0..143
  int bx = r % 9;            // fastest: consecutive blocks share B y-panel
  int by = r / 9;            // 0..15
  int Me = counts[e];
  int m0 = bx * 256;
  if (m0 >= Me) return;
  int n0 = by * 128;
  int oe = offs[e];
  const int* tle = tl + oe;

  int lane = tid & 63;
  int wid = tid >> 6;        // 0..7
  int wm = wid >> 2;         // 0..1
  int wn = wid & 3;          // 0..3

  __shared__ u16 lds[2][2][256 * 64];  // 128 KiB

  int lr = lane >> 3;
  int swz = ((lane & 7) ^ lr) * 8;     // pre-swizzled source slot
  const u16* pA[4];
  const u16* pB[4];
#pragma unroll
  for (int j = 0; j < 4; j++) {
    int c = j * 8 + wid;               // 0..31
    int a = m0 + c * 8 + lr;
    if (a >= Me) a = Me - 1;
    pA[j] = xb + (size_t)tle[a] * DM + swz;
    int b = c * 8 + lr;                // 0..255
    int grow = ((b >> 5) & 1) * DFF + n0 + ((b >> 6) & 3) * 32 + (b & 31);
    pB[j] = wgu + ((size_t)e * 2 * DFF + grow) * DM + swz;
  }

  f32x4 acc[8][4];
#pragma unroll
  for (int m = 0; m < 8; m++)
#pragma unroll
    for (int f = 0; f < 4; f++) acc[m][f] = (f32x4){0.f, 0.f, 0.f, 0.f};

  const int r15 = lane & 15;
  const int hi4 = lane >> 4;
  const int rx = r15 & 7;

#pragma unroll
  for (int j = 0; j < 4; j++) {
    int off = (j * 8 + wid) * 1024;
    async16(pA[j], (char*)&lds[0][0][0] + off);
    async16(pB[j], (char*)&lds[0][1][0] + off);
  }
  asm volatile("s_waitcnt vmcnt(0)" ::: "memory");
  __builtin_amdgcn_s_barrier();
  __builtin_amdgcn_sched_barrier(0);

  int cur = 0;
#pragma unroll 1
  for (int t = 0; t < DM / 64; t++) {
    const char* Ab = (const char*)&lds[cur][0][0];
    const char* Bb = (const char*)&lds[cur][1][0];
    char* LA = (char*)&lds[cur ^ 1][0][0];
    char* LB = (char*)&lds[cur ^ 1][1][0];
    int k1 = (t + 1) * 64;
    bool pf = (t < DM / 64 - 1);
    bf16x8 bfr[4][2];
#pragma unroll
    for (int p = 0; p < 4; p++) {
      if (p == 0) {
#pragma unroll
        for (int f = 0; f < 4; f++)
#pragma unroll
          for (int kk = 0; kk < 2; kk++) {
            int row = wn * 64 + f * 16 + r15;
            bfr[f][kk] = *(const bf16x8*)(Bb + row * 128 + (((kk * 4 + hi4) ^ rx) * 16));
          }
      }
      bf16x8 af[2][2];
#pragma unroll
      for (int i = 0; i < 2; i++)
#pragma unroll
        for (int kk = 0; kk < 2; kk++) {
          int row = wm * 128 + (2 * p + i) * 16 + r15;
          af[i][kk] = *(const bf16x8*)(Ab + row * 128 + (((kk * 4 + hi4) ^ rx) * 16));
        }
      if (pf && p < 2) {
#pragma unroll
        for (int j = 0; j < 2; j++) {
          int jj = p * 2 + j;
          int off = (jj * 8 + wid) * 1024;
          async16(pA[jj] + k1, LA + off);
          async16(pB[jj] + k1, LB + off);
        }
      }
      __builtin_amdgcn_sched_barrier(0);
      __builtin_amdgcn_s_setprio(1);
#pragma unroll
      for (int kk = 0; kk < 2; kk++)
#pragma unroll
        for (int i = 0; i < 2; i++)
#pragma unroll
          for (int f = 0; f < 4; f++)
            acc[2 * p + i][f] = __builtin_amdgcn_mfma_f32_16x16x32_bf16(
                af[i][kk], bfr[f][kk], acc[2 * p + i][f], 0, 0, 0);
      __builtin_amdgcn_s_setprio(0);
      __builtin_amdgcn_sched_barrier(0);
    }
    asm volatile("s_waitcnt vmcnt(0)" ::: "memory");
    __builtin_amdgcn_s_barrier();
    __builtin_amdgcn_sched_barrier(0);
    cur ^= 1;
  }

  int colb = n0 + wn * 32 + r15;
#pragma unroll
  for (int m = 0; m < 8; m++) {
#pragma unroll
    for (int rr = 0; rr < 4; rr++) {
      int gm = m0 + wm * 128 + m * 16 + hi4 * 4 + rr;
      if (gm < Me) {
        size_t rowp = (size_t)(oe + gm) * DFF;
#pragma unroll
        for (int f = 0; f < 2; f++) {
          float g = acc[m][f][rr];
          float u = acc[m][f + 2][rr];
          float s = g / (1.0f + __expf(-g));
          hid[rowp + colb + f * 16] = f2bf(s * u);
        }
      }
    }
  }
}

// ---------------- GEMM2 main: rows [0,2048), EXACTLY 256 blocks ----
__global__ __launch_bounds__(512, 2) void k_gemm2(
    const u16* __restrict__ hid, const u16* __restrict__ wd,
    float* __restrict__ out, const int* __restrict__ tl,
    const int* __restrict__ offs, const int* __restrict__ counts) {
  int wg = blockIdx.x;
  int e = wg & 7;
  int r = wg >> 3;           // 0..31
  int bx = r & 7;            // 0..7
  int by = r >> 3;           // 0..3
  int Me = counts[e];
  int m0 = bx * 256;
  if (m0 >= Me) return;
  int n0 = by * 256;
  int oe = offs[e];
  const int* tle = tl + oe;

  int tid = threadIdx.x;
  int lane = tid & 63;
  int wid = tid >> 6;
  int wm = wid >> 2;         // 0..1
  int wn = wid & 3;          // 0..3

  __shared__ u16 lds[2][2][256 * 64];  // 128 KiB

  int lr = lane >> 3;
  int swz = ((lane & 7) ^ lr) * 8;
  const u16* pA[4];
  const u16* pB[4];
#pragma unroll
  for (int j = 0; j < 4; j++) {
    int c = j * 8 + wid;               // 0..31
    int a = m0 + c * 8 + lr;
    if (a >= Me) a = Me - 1;
    pA[j] = hid + (size_t)(oe + a) * DFF + swz;
    pB[j] = wd + ((size_t)e * DM + n0 + c * 8 + lr) * DFF + swz;
  }

  f32x4 acc[8][4];
#pragma unroll
  for (int m = 0; m < 8; m++)
#pragma unroll
    for (int f = 0; f < 4; f++) acc[m][f] = (f32x4){0.f, 0.f, 0.f, 0.f};

  const int r15 = lane & 15;
  const int hi4 = lane >> 4;
  const int rx = r15 & 7;

#pragma unroll
  for (int j = 0; j < 4; j++) {
    int off = (j * 8 + wid) * 1024;
    async16(pA[j], (char*)&lds[0][0][0] + off);
    async16(pB[j], (char*)&lds[0][1][0] + off);
  }
  asm volatile("s_waitcnt vmcnt(0)" ::: "memory");
  __builtin_amdgcn_s_barrier();
  __builtin_amdgcn_sched_barrier(0);

  int cur = 0;
#pragma unroll 1
  for (int t = 0; t < DFF / 64; t++) {
    const char* Ab = (const char*)&lds[cur][0][0];
    const char* Bb = (const char*)&lds[cur][1][0];
    char* LA = (char*)&lds[cur ^ 1][0][0];
    char* LB = (char*)&lds[cur ^ 1][1][0];
    int k1 = (t + 1) * 64;
    bool pf = (t < DFF / 64 - 1);
    bf16x8 bfr[4][2];
#pragma unroll
    for (int p = 0; p < 4; p++) {
      if (p == 0) {
#pragma unroll
        for (int f = 0; f < 4; f++)
#pragma unroll
          for (int kk = 0; kk < 2; kk++) {
            int row = wn * 64 + f * 16 + r15;
            bfr[f][kk] = *(const bf16x8*)(Bb + row * 128 + (((kk * 4 + hi4) ^ rx) * 16));
          }
      }
      bf16x8 af[2][2];
#pragma unroll
      for (int i = 0; i < 2; i++)
#pragma unroll
        for (int kk = 0; kk < 2; kk++) {
          int row = wm * 128 + (2 * p + i) * 16 + r15;
          af[i][kk] = *(const bf16x8*)(Ab + row * 128 + (((kk * 4 + hi4) ^ rx) * 16));
        }
      if (pf && p < 2) {
#pragma unroll
        for (int j = 0; j < 2; j++) {
          int jj = p * 2 + j;
          int off = (jj * 8 + wid) * 1024;
          async16(pA[jj] + k1, LA + off);
          async16(pB[jj] + k1, LB + off);
        }
      }
      __builtin_amdgcn_sched_barrier(0);
      __builtin_amdgcn_s_setprio(1);
#pragma unroll
      for (int kk = 0; kk < 2; kk++)
#pragma unroll
        for (int i = 0; i < 2; i++)
#pragma unroll
          for (int f = 0; f < 4; f++)
            acc[2 * p + i][f] = __builtin_amdgcn_mfma_f32_16x16x32_bf16(
                af[i][kk], bfr[f][kk], acc[2 * p + i][f], 0, 0, 0);
      __builtin_amdgcn_s_setprio(0);
      __builtin_amdgcn_sched_barrier(0);
    }
    asm volatile("s_waitcnt vmcnt(0)" ::: "memory");
    __builtin_amdgcn_s_barrier();
    __builtin_amdgcn_sched_barrier(0);
    cur ^= 1;
  }

  int colb = n0 + wn * 64 + r15;
#pragma unroll
  for (int m = 0; m < 8; m++) {
#pragma unroll
    for (int rr = 0; rr < 4; rr++) {
      int gm = m0 + wm * 128 + m * 16 + hi4 * 4 + rr;
      if (gm < Me) {
        int tk = tle[gm];
#pragma unroll
        for (int f = 0; f < 4; f++)
          out[(size_t)tk * DM + colb + f * 16] = acc[m][f][rr];
      }
    }
  }
}

// ---------------- GEMM2 overflow: rows [2048, 2304), BM=64 ----------------
__global__ __launch_bounds__(512, 2) void k_gemm2_ovf(
    const u16* __restrict__ hid, const u16* __restrict__ wd,
    float* __restrict__ out, const int* __restrict__ tl,
    const int* __restrict__ offs, const int* __restrict__ counts) {
  int wg = blockIdx.x;
  int e = wg & 7;
  int r = wg >> 3;           // 0..15
  int bx = r & 3;            // 0..3
  int by = r >> 2;           // 0..3
  int Me = counts[e];
  int m0 = 2048 + bx * 64;
  if (m0 >= Me) return;
  int n0 = by * 256;
  int oe = offs[e];
  const int* tle = tl + oe;

  int tid = threadIdx.x;
  int lane = tid & 63;
  int wid = tid >> 6;        // 0..7
  int wm = wid >> 2;         // 0..1
  int wn = wid & 3;          // 0..3

  __shared__ u16 ldsA[2][64 * 64];   // 16 KiB
  __shared__ u16 ldsB[2][256 * 64];  // 64 KiB

  int lr = lane >> 3;
  int swz = ((lane & 7) ^ lr) * 8;
  const u16* pAo;
  const u16* pB[4];
  {
    int a = m0 + wid * 8 + lr;
    if (a >= Me) a = Me - 1;
    pAo = hid + (size_t)(oe + a) * DFF + swz;
  }
#pragma unroll
  for (int j = 0; j < 4; j++) {
    int c = j * 8 + wid;
    pB[j] = wd + ((size_t)e * DM + n0 + c * 8 + lr) * DFF + swz;
  }

  f32x4 acc[2][4];
#pragma unroll
  for (int m = 0; m < 2; m++)
#pragma unroll
    for (int f = 0; f < 4; f++) acc[m][f] = (f32x4){0.f, 0.f, 0.f, 0.f};

  const int r15 = lane & 15;
  const int hi4 = lane >> 4;
  const int rx = r15 & 7;

  async16(pAo, (char*)&ldsA[0][0] + wid * 1024);
#pragma unroll
  for (int j = 0; j < 4; j++)
    async16(pB[j], (char*)&ldsB[0][0] + (j * 8 + wid) * 1024);
  asm volatile("s_waitcnt vmcnt(0)" ::: "memory");
  __builtin_amdgcn_s_barrier();
  __builtin_amdgcn_sched_barrier(0);

  int cur = 0;
#pragma unroll 1
  for (int t = 0; t < DFF / 64; t++) {
    const char* Ab = (const char*)&ldsA[cur][0];
    const char* Bb = (const char*)&ldsB[cur][0];
    char* LA = (char*)&ldsA[cur ^ 1][0];
    char* LB = (char*)&ldsB[cur ^ 1][0];
    int k1 = (t + 1) * 64;
    bool pf = (t < DFF / 64 - 1);
#pragma unroll
    for (int kk = 0; kk < 2; kk++) {
      bf16x8 bfr[4], af[2];
#pragma unroll
      for (int f = 0; f < 4; f++) {
        int row = wn * 64 + f * 16 + r15;
        bfr[f] = *(const bf16x8*)(Bb + row * 128 + (((kk * 4 + hi4) ^ rx) * 16));
      }
#pragma unroll
      for (int i = 0; i < 2; i++) {
        int row = wm * 32 + i * 16 + r15;
        af[i] = *(const bf16x8*)(Ab + row * 128 + (((kk * 4 + hi4) ^ rx) * 16));
      }
      if (pf) {
        if (kk == 0) {
          async16(pAo + k1, LA + wid * 1024);
#pragma unroll
          for (int j = 0; j < 2; j++)
            async16(pB[j] + k1, LB + (j * 8 + wid) * 1024);
        } else {
#pragma unroll
          for (int j = 2; j < 4; j++)
            async16(pB[j] + k1, LB + (j * 8 + wid) * 1024);
        }
      }
      __builtin_amdgcn_sched_barrier(0);
      __builtin_amdgcn_s_setprio(1);
#pragma unroll
      for (int i = 0; i < 2; i++)
#pragma unroll
        for (int f = 0; f < 4; f++)
          acc[i][f] = __builtin_amdgcn_mfma_f32_16x16x32_bf16(af[i], bfr[f], acc[i][f], 0, 0, 0);
      __builtin_amdgcn_s_setprio(0);
      __builtin_amdgcn_sched_barrier(0);
    }
    asm volatile("s_waitcnt vmcnt(0)" ::: "memory");
    __builtin_amdgcn_s_barrier();
    __builtin_amdgcn_sched_barrier(0);
    cur ^= 1;
  }

  int colb = n0 + wn * 64 + r15;
#pragma unroll
  for (int m = 0; m < 2; m++) {
#pragma unroll
    for (int rr = 0; rr < 4; rr++) {
      int gm = m0 + wm * 32 + m * 16 + hi4 * 4 + rr;
      if (gm < Me) {
        int tk = tle[gm];
#pragma unroll
        for (int f = 0; f < 4; f++)
          out[(size_t)tk * DM + colb + f * 16] = acc[m][f][rr];
      }
    }
  }
}

extern "C" void kernel_launch(void* const* d_in, const int* in_sizes, int n_in,
                              void* d_out, int out_size, void* d_ws, size_t ws_size,
                              hipStream_t stream) {
  const float* x   = (const float*)d_in[0];
  const int* eidx  = (const int*)d_in[1];
  const float* wgu = (const float*)d_in[2];
  const float* wd  = (const float*)d_in[3];
  float* out = (float*)d_out;
  char* ws = (char*)d_ws;

  int* ctrl = (int*)ws;                          // counts[8], offs[8], cursor[8]
  int* toklist = (int*)(ws + 256);               // 16384 ints
  u16* xb   = (u16*)(ws + 65792);                // 32 MB
  u16* wgub = (u16*)(ws + 65792 + 33554432ull);  // 64 MB
  u16* wdb  = (u16*)(ws + 65792 + 33554432ull + 67108864ull);   // 32 MB
  u16* hid  = (u16*)(ws + 65792 + 33554432ull + 67108864ull + 33554432ull);  // 64 MB

  hipMemsetAsync(ws, 0, 256, stream);
  k_count<<<NTOK / 256, 256, 0, stream>>>(eidx, ctrl);
  k_offsets<<<1, 64, 0, stream>>>(ctrl);
  k_scatter<<<NTOK / 256, 256, 0, stream>>>(eidx, ctrl + 16, toklist);

  k_cvt_xw<<<2048, 256, 0, stream>>>(x, wgu, xb, wgub);

  // counts ~2048 +- 42 (seed-fixed). g1: 9 M-blocks of 256 (2304 = 6 sigma).
  k_gemm1<<<9 * 16 * NE, 512, 0, stream>>>(xb, wgub, hid, toklist, ctrl + 8, ctrl, wd, wdb);
  // g2: main covers rows < 2048 with EXACTLY 256 blocks (1 dispatch round);
  // overflow kernel covers rows [2048, 2304).
  k_gemm2<<<8 * 4 * NE, 512, 0, stream>>>(hid, wdb, out, toklist, ctrl + 8, ctrl);
  k_gemm2_ovf<<<4 * 4 * NE, 512, 0, stream>>>(hid, wdb, out, toklist, ctrl + 8, ctrl);
}

// Round 18
// 451.435 us; speedup vs baseline: 1.2197x; 1.0325x over previous
//
#include <hip/hip_runtime.h>

#define NTOK 16384
#define DM 1024
#define DFF 2048
#define NE 8

typedef unsigned short u16;
typedef __attribute__((ext_vector_type(8))) short bf16x8;
typedef __attribute__((ext_vector_type(4))) float f32x4;

__device__ __forceinline__ u16 f2bf(float f) {
  unsigned u = __float_as_uint(f);
  u += 0x7fff + ((u >> 16) & 1);
  return (u16)(u >> 16);
}

__device__ __forceinline__ void async16(const void* g, void* l) {
  __builtin_amdgcn_global_load_lds(
      (const __attribute__((address_space(1))) unsigned int*)g,
      (__attribute__((address_space(3))) unsigned int*)l, 16, 0, 0);
}

// ---------------- routing ----------------
__global__ void k_count(const int* __restrict__ idx, int* __restrict__ counts) {
  int t = blockIdx.x * 256 + threadIdx.x;
  atomicAdd(&counts[idx[t]], 1);
}

__global__ void k_offsets(int* __restrict__ c) {
  if (threadIdx.x == 0) {
    int acc = 0;
    for (int e = 0; e < NE; e++) { c[8 + e] = acc; c[16 + e] = acc; acc += c[e]; }
  }
}

__global__ void k_scatter(const int* __restrict__ idx, int* __restrict__ cursor,
                          int* __restrict__ tl) {
  int t = blockIdx.x * 256 + threadIdx.x;
  int pos = atomicAdd(&cursor[idx[t]], 1);
  tl[pos] = t;
}

// ---------------- fp32 -> bf16 conversion: x + wgu only ----------------
__global__ void k_cvt_xw(const float* __restrict__ x, const float* __restrict__ wgu,
                         u16* __restrict__ xb, u16* __restrict__ wgub) {
  const size_t N1 = (size_t)NTOK * DM;
  const size_t N2 = (size_t)NE * 2 * DFF * DM;
  const size_t total4 = (N1 + N2) / 4;
  for (size_t q = (size_t)blockIdx.x * 256 + threadIdx.x; q < total4;
       q += (size_t)gridDim.x * 256) {
    size_t i = q * 4;
    const float* s;
    u16* d;
    if (i < N1) { s = x + i; d = xb + i; }
    else { s = wgu + (i - N1); d = wgub + (i - N1); }
    float4 v = *(const float4*)s;
    ushort4 o;
    o.x = f2bf(v.x); o.y = f2bf(v.y); o.z = f2bf(v.z); o.w = f2bf(v.w);
    *(ushort4*)d = o;
  }
}

// ---------------- GEMM1: hidden = silu(x@Wg^T) * (x@Wu^T) ----------------
// r6 geometry + barrier diet + serial wd->wdb fold prologue (r12 form).
__global__ __launch_bounds__(512, 2) void k_gemm1(
    const u16* __restrict__ xb, const u16* __restrict__ wgu,
    u16* __restrict__ hid, const int* __restrict__ tl,
    const int* __restrict__ offs, const int* __restrict__ counts,
    const float* __restrict__ wd, u16* __restrict__ wdb) {
  int wg = blockIdx.x;
  int tid = threadIdx.x;

  // ---- wd fp32 -> bf16 fold (all 1152 blocks participate) ----
  {
    const size_t WD4 = (size_t)NE * DM * DFF / 4;
    for (size_t i = (size_t)wg * 512 + tid; i < WD4; i += (size_t)1152 * 512) {
      float4 v = *(const float4*)(wd + i * 4);
      ushort4 o;
      o.x = f2bf(v.x); o.y = f2bf(v.y); o.z = f2bf(v.z); o.w = f2bf(v.w);
      *(ushort4*)(wdb + i * 4) = o;
    }
  }

  int e = wg & 7;            // expert -> XCD pin
  int r = wg >> 3;           // 0..143
  int bx = r % 9;            // fastest: consecutive blocks share B y-panel
  int by = r / 9;            // 0..15
  int Me = counts[e];
  int m0 = bx * 256;
  if (m0 >= Me) return;
  int n0 = by * 128;
  int oe = offs[e];
  const int* tle = tl + oe;

  int lane = tid & 63;
  int wid = tid >> 6;        // 0..7
  int wm = wid >> 2;         // 0..1
  int wn = wid & 3;          // 0..3

  __shared__ u16 lds[2][2][256 * 64];  // 128 KiB

  int lr = lane >> 3;
  int swz = ((lane & 7) ^ lr) * 8;     // pre-swizzled source slot
  const u16* pA[4];
  const u16* pB[4];
#pragma unroll
  for (int j = 0; j < 4; j++) {
    int c = j * 8 + wid;               // 0..31
    int a = m0 + c * 8 + lr;
    if (a >= Me) a = Me - 1;
    pA[j] = xb + (size_t)tle[a] * DM + swz;
    int b = c * 8 + lr;                // 0..255
    int grow = ((b >> 5) & 1) * DFF + n0 + ((b >> 6) & 3) * 32 + (b & 31);
    pB[j] = wgu + ((size_t)e * 2 * DFF + grow) * DM + swz;
  }

  f32x4 acc[8][4];
#pragma unroll
  for (int m = 0; m < 8; m++)
#pragma unroll
    for (int f = 0; f < 4; f++) acc[m][f] = (f32x4){0.f, 0.f, 0.f, 0.f};

  const int r15 = lane & 15;
  const int hi4 = lane >> 4;
  const int rx = r15 & 7;

#pragma unroll
  for (int j = 0; j < 4; j++) {
    int off = (j * 8 + wid) * 1024;
    async16(pA[j], (char*)&lds[0][0][0] + off);
    async16(pB[j], (char*)&lds[0][1][0] + off);
  }
  asm volatile("s_waitcnt vmcnt(0)" ::: "memory");
  __builtin_amdgcn_s_barrier();
  __builtin_amdgcn_sched_barrier(0);

  int cur = 0;
#pragma unroll 1
  for (int t = 0; t < DM / 64; t++) {
    const char* Ab = (const char*)&lds[cur][0][0];
    const char* Bb = (const char*)&lds[cur][1][0];
    char* LA = (char*)&lds[cur ^ 1][0][0];
    char* LB = (char*)&lds[cur ^ 1][1][0];
    int k1 = (t + 1) * 64;
    bool pf = (t < DM / 64 - 1);
    bf16x8 bfr[4][2];
#pragma unroll
    for (int p = 0; p < 4; p++) {
      if (p == 0) {
#pragma unroll
        for (int f = 0; f < 4; f++)
#pragma unroll
          for (int kk = 0; kk < 2; kk++) {
            int row = wn * 64 + f * 16 + r15;
            bfr[f][kk] = *(const bf16x8*)(Bb + row * 128 + (((kk * 4 + hi4) ^ rx) * 16));
          }
      }
      bf16x8 af[2][2];
#pragma unroll
      for (int i = 0; i < 2; i++)
#pragma unroll
        for (int kk = 0; kk < 2; kk++) {
          int row = wm * 128 + (2 * p + i) * 16 + r15;
          af[i][kk] = *(const bf16x8*)(Ab + row * 128 + (((kk * 4 + hi4) ^ rx) * 16));
        }
      if (pf && p < 2) {
#pragma unroll
        for (int j = 0; j < 2; j++) {
          int jj = p * 2 + j;
          int off = (jj * 8 + wid) * 1024;
          async16(pA[jj] + k1, LA + off);
          async16(pB[jj] + k1, LB + off);
        }
      }
      __builtin_amdgcn_sched_barrier(0);
      __builtin_amdgcn_s_setprio(1);
#pragma unroll
      for (int kk = 0; kk < 2; kk++)
#pragma unroll
        for (int i = 0; i < 2; i++)
#pragma unroll
          for (int f = 0; f < 4; f++)
            acc[2 * p + i][f] = __builtin_amdgcn_mfma_f32_16x16x32_bf16(
                af[i][kk], bfr[f][kk], acc[2 * p + i][f], 0, 0, 0);
      __builtin_amdgcn_s_setprio(0);
      __builtin_amdgcn_sched_barrier(0);
    }
    asm volatile("s_waitcnt vmcnt(0)" ::: "memory");
    __builtin_amdgcn_s_barrier();
    __builtin_amdgcn_sched_barrier(0);
    cur ^= 1;
  }

  int colb = n0 + wn * 32 + r15;
#pragma unroll
  for (int m = 0; m < 8; m++) {
#pragma unroll
    for (int rr = 0; rr < 4; rr++) {
      int gm = m0 + wm * 128 + m * 16 + hi4 * 4 + rr;
      if (gm < Me) {
        size_t rowp = (size_t)(oe + gm) * DFF;
#pragma unroll
        for (int f = 0; f < 2; f++) {
          float g = acc[m][f][rr];
          float u = acc[m][f + 2][rr];
          float s = g / (1.0f + __expf(-g));
          hid[rowp + colb + f * 16] = f2bf(s * u);
        }
      }
    }
  }
}

// ---------------- GEMM2 main: rows [0,2048), EXACTLY 256 blocks ----
__global__ __launch_bounds__(512, 2) void k_gemm2(
    const u16* __restrict__ hid, const u16* __restrict__ wd,
    float* __restrict__ out, const int* __restrict__ tl,
    const int* __restrict__ offs, const int* __restrict__ counts) {
  int wg = blockIdx.x;
  int e = wg & 7;
  int r = wg >> 3;           // 0..31
  int bx = r & 7;            // 0..7
  int by = r >> 3;           // 0..3
  int Me = counts[e];
  int m0 = bx * 256;
  if (m0 >= Me) return;
  int n0 = by * 256;
  int oe = offs[e];
  const int* tle = tl + oe;

  int tid = threadIdx.x;
  int lane = tid & 63;
  int wid = tid >> 6;
  int wm = wid >> 2;         // 0..1
  int wn = wid & 3;          // 0..3

  __shared__ u16 lds[2][2][256 * 64];  // 128 KiB

  int lr = lane >> 3;
  int swz = ((lane & 7) ^ lr) * 8;
  const u16* pA[4];
  const u16* pB[4];
#pragma unroll
  for (int j = 0; j < 4; j++) {
    int c = j * 8 + wid;               // 0..31
    int a = m0 + c * 8 + lr;
    if (a >= Me) a = Me - 1;
    pA[j] = hid + (size_t)(oe + a) * DFF + swz;
    pB[j] = wd + ((size_t)e * DM + n0 + c * 8 + lr) * DFF + swz;
  }

  f32x4 acc[8][4];
#pragma unroll
  for (int m = 0; m < 8; m++)
#pragma unroll
    for (int f = 0; f < 4; f++) acc[m][f] = (f32x4){0.f, 0.f, 0.f, 0.f};

  const int r15 = lane & 15;
  const int hi4 = lane >> 4;
  const int rx = r15 & 7;

#pragma unroll
  for (int j = 0; j < 4; j++) {
    int off = (j * 8 + wid) * 1024;
    async16(pA[j], (char*)&lds[0][0][0] + off);
    async16(pB[j], (char*)&lds[0][1][0] + off);
  }
  asm volatile("s_waitcnt vmcnt(0)" ::: "memory");
  __builtin_amdgcn_s_barrier();
  __builtin_amdgcn_sched_barrier(0);

  int cur = 0;
#pragma unroll 1
  for (int t = 0; t < DFF / 64; t++) {
    const char* Ab = (const char*)&lds[cur][0][0];
    const char* Bb = (const char*)&lds[cur][1][0];
    char* LA = (char*)&lds[cur ^ 1][0][0];
    char* LB = (char*)&lds[cur ^ 1][1][0];
    int k1 = (t + 1) * 64;
    bool pf = (t < DFF / 64 - 1);
    bf16x8 bfr[4][2];
#pragma unroll
    for (int p = 0; p < 4; p++) {
      if (p == 0) {
#pragma unroll
        for (int f = 0; f < 4; f++)
#pragma unroll
          for (int kk = 0; kk < 2; kk++) {
            int row = wn * 64 + f * 16 + r15;
            bfr[f][kk] = *(const bf16x8*)(Bb + row * 128 + (((kk * 4 + hi4) ^ rx) * 16));
          }
      }
      bf16x8 af[2][2];
#pragma unroll
      for (int i = 0; i < 2; i++)
#pragma unroll
        for (int kk = 0; kk < 2; kk++) {
          int row = wm * 128 + (2 * p + i) * 16 + r15;
          af[i][kk] = *(const bf16x8*)(Ab + row * 128 + (((kk * 4 + hi4) ^ rx) * 16));
        }
      if (pf && p < 2) {
#pragma unroll
        for (int j = 0; j < 2; j++) {
          int jj = p * 2 + j;
          int off = (jj * 8 + wid) * 1024;
          async16(pA[jj] + k1, LA + off);
          async16(pB[jj] + k1, LB + off);
        }
      }
      __builtin_amdgcn_sched_barrier(0);
      __builtin_amdgcn_s_setprio(1);
#pragma unroll
      for (int kk = 0; kk < 2; kk++)
#pragma unroll
        for (int i = 0; i < 2; i++)
#pragma unroll
          for (int f = 0; f < 4; f++)
            acc[2 * p + i][f] = __builtin_amdgcn_mfma_f32_16x16x32_bf16(
                af[i][kk], bfr[f][kk], acc[2 * p + i][f], 0, 0, 0);
      __builtin_amdgcn_s_setprio(0);
      __builtin_amdgcn_sched_barrier(0);
    }
    asm volatile("s_waitcnt vmcnt(0)" ::: "memory");
    __builtin_amdgcn_s_barrier();
    __builtin_amdgcn_sched_barrier(0);
    cur ^= 1;
  }

  int colb = n0 + wn * 64 + r15;
#pragma unroll
  for (int m = 0; m < 8; m++) {
#pragma unroll
    for (int rr = 0; rr < 4; rr++) {
      int gm = m0 + wm * 128 + m * 16 + hi4 * 4 + rr;
      if (gm < Me) {
        int tk = tle[gm];
#pragma unroll
        for (int f = 0; f < 4; f++)
          out[(size_t)tk * DM + colb + f * 16] = acc[m][f][rr];
      }
    }
  }
}

// ---------------- GEMM2 overflow: rows [2048, 2304), BM=64 x BN=64 ----------
// Thin-quantum rework: 32 KiB LDS -> 5 blocks/CU; grid 4bx x 16by x 8e = 512
// blocks (~64-128 active), each ~33 MF, all co-resident -> one short round.
// 8 waves (2M x 4N, wave 32x16), acc[2]; 1 staging chunk/wave/operand.
__global__ __launch_bounds__(512, 2) void k_gemm2_ovf(
    const u16* __restrict__ hid, const u16* __restrict__ wd,
    float* __restrict__ out, const int* __restrict__ tl,
    const int* __restrict__ offs, const int* __restrict__ counts) {
  int wg = blockIdx.x;
  int e = wg & 7;
  int r = wg >> 3;           // 0..63
  int bx = r & 3;            // 0..3
  int by = r >> 2;           // 0..15
  int Me = counts[e];
  int m0 = 2048 + bx * 64;
  if (m0 >= Me) return;
  int n0 = by * 64;
  int oe = offs[e];
  const int* tle = tl + oe;

  int tid = threadIdx.x;
  int lane = tid & 63;
  int wid = tid >> 6;        // 0..7
  int wm = wid >> 2;         // 0..1
  int wn = wid & 3;          // 0..3

  __shared__ u16 ldsA[2][64 * 64];   // 16 KiB
  __shared__ u16 ldsB[2][64 * 64];   // 16 KiB

  int lr = lane >> 3;
  int swz = ((lane & 7) ^ lr) * 8;
  const u16* pAo;
  const u16* pBo;
  {
    int a = m0 + wid * 8 + lr;
    if (a >= Me) a = Me - 1;
    pAo = hid + (size_t)(oe + a) * DFF + swz;
    pBo = wd + ((size_t)e * DM + n0 + wid * 8 + lr) * DFF + swz;
  }

  f32x4 acc[2];
#pragma unroll
  for (int m = 0; m < 2; m++) acc[m] = (f32x4){0.f, 0.f, 0.f, 0.f};

  const int r15 = lane & 15;
  const int hi4 = lane >> 4;
  const int rx = r15 & 7;

  async16(pAo, (char*)&ldsA[0][0] + wid * 1024);
  async16(pBo, (char*)&ldsB[0][0] + wid * 1024);
  asm volatile("s_waitcnt vmcnt(0)" ::: "memory");
  __builtin_amdgcn_s_barrier();
  __builtin_amdgcn_sched_barrier(0);

  int cur = 0;
#pragma unroll 1
  for (int t = 0; t < DFF / 64; t++) {
    const char* Ab = (const char*)&ldsA[cur][0];
    const char* Bb = (const char*)&ldsB[cur][0];
    char* LA = (char*)&ldsA[cur ^ 1][0];
    char* LB = (char*)&ldsB[cur ^ 1][0];
    int k1 = (t + 1) * 64;
    bool pf = (t < DFF / 64 - 1);
    bf16x8 bfr[2], af[2][2];
#pragma unroll
    for (int kk = 0; kk < 2; kk++) {
      int row = wn * 16 + r15;
      bfr[kk] = *(const bf16x8*)(Bb + row * 128 + (((kk * 4 + hi4) ^ rx) * 16));
#pragma unroll
      for (int i = 0; i < 2; i++) {
        int arow = wm * 32 + i * 16 + r15;
        af[i][kk] = *(const bf16x8*)(Ab + arow * 128 + (((kk * 4 + hi4) ^ rx) * 16));
      }
    }
    if (pf) {
      async16(pAo + k1, LA + wid * 1024);
      async16(pBo + k1, LB + wid * 1024);
    }
    __builtin_amdgcn_sched_barrier(0);
    __builtin_amdgcn_s_setprio(1);
#pragma unroll
    for (int kk = 0; kk < 2; kk++)
#pragma unroll
      for (int i = 0; i < 2; i++)
        acc[i] = __builtin_amdgcn_mfma_f32_16x16x32_bf16(af[i][kk], bfr[kk], acc[i], 0, 0, 0);
    __builtin_amdgcn_s_setprio(0);
    __builtin_amdgcn_sched_barrier(0);
    asm volatile("s_waitcnt vmcnt(0)" ::: "memory");
    __builtin_amdgcn_s_barrier();
    __builtin_amdgcn_sched_barrier(0);
    cur ^= 1;
  }

  int colb = n0 + wn * 16 + r15;
#pragma unroll
  for (int m = 0; m < 2; m++) {
#pragma unroll
    for (int rr = 0; rr < 4; rr++) {
      int gm = m0 + wm * 32 + m * 16 + hi4 * 4 + rr;
      if (gm < Me) {
        int tk = tle[gm];
        out[(size_t)tk * DM + colb] = acc[m][rr];
      }
    }
  }
}

extern "C" void kernel_launch(void* const* d_in, const int* in_sizes, int n_in,
                              void* d_out, int out_size, void* d_ws, size_t ws_size,
                              hipStream_t stream) {
  const float* x   = (const float*)d_in[0];
  const int* eidx  = (const int*)d_in[1];
  const float* wgu = (const float*)d_in[2];
  const float* wd  = (const float*)d_in[3];
  float* out = (float*)d_out;
  char* ws = (char*)d_ws;

  int* ctrl = (int*)ws;                          // counts[8], offs[8], cursor[8]
  int* toklist = (int*)(ws + 256);               // 16384 ints
  u16* xb   = (u16*)(ws + 65792);                // 32 MB
  u16* wgub = (u16*)(ws + 65792 + 33554432ull);  // 64 MB
  u16* wdb  = (u16*)(ws + 65792 + 33554432ull + 67108864ull);   // 32 MB
  u16* hid  = (u16*)(ws + 65792 + 33554432ull + 67108864ull + 33554432ull);  // 64 MB

  hipMemsetAsync(ws, 0, 256, stream);
  k_count<<<NTOK / 256, 256, 0, stream>>>(eidx, ctrl);
  k_offsets<<<1, 64, 0, stream>>>(ctrl);
  k_scatter<<<NTOK / 256, 256, 0, stream>>>(eidx, ctrl + 16, toklist);

  k_cvt_xw<<<2048, 256, 0, stream>>>(x, wgu, xb, wgub);

  // counts ~2048 +- 42 (seed-fixed). g1: 9 M-blocks of 256 (2304 = 6 sigma).
  k_gemm1<<<9 * 16 * NE, 512, 0, stream>>>(xb, wgub, hid, toklist, ctrl + 8, ctrl, wd, wdb);
  // g2: main covers rows < 2048 with EXACTLY 256 blocks (1 dispatch round);
  // thin overflow kernel (512 x 32KiB blocks, all co-resident) covers the rest.
  k_gemm2<<<8 * 4 * NE, 512, 0, stream>>>(hid, wdb, out, toklist, ctrl + 8, ctrl);
  k_gemm2_ovf<<<4 * 16 * NE, 512, 0, stream>>>(hid, wdb, out, toklist, ctrl + 8, ctrl);
}

// Round 19
// 450.084 us; speedup vs baseline: 1.2233x; 1.0030x over previous
//
#include <hip/hip_runtime.h>

#define NTOK 16384
#define DM 1024
#define DFF 2048
#define NE 8

typedef unsigned short u16;
typedef __attribute__((ext_vector_type(8))) short bf16x8;
typedef __attribute__((ext_vector_type(4))) float f32x4;

__device__ __forceinline__ u16 f2bf(float f) {
  unsigned u = __float_as_uint(f);
  u += 0x7fff + ((u >> 16) & 1);
  return (u16)(u >> 16);
}

__device__ __forceinline__ void async16(const void* g, void* l) {
  __builtin_amdgcn_global_load_lds(
      (const __attribute__((address_space(1))) unsigned int*)g,
      (__attribute__((address_space(3))) unsigned int*)l, 16, 0, 0);
}

// ---------------- routing ----------------
__global__ void k_count(const int* __restrict__ idx, int* __restrict__ counts) {
  int t = blockIdx.x * 256 + threadIdx.x;
  atomicAdd(&counts[idx[t]], 1);
}

__global__ void k_offsets(int* __restrict__ c) {
  if (threadIdx.x == 0) {
    int acc = 0;
    for (int e = 0; e < NE; e++) { c[8 + e] = acc; c[16 + e] = acc; acc += c[e]; }
  }
}

__global__ void k_scatter(const int* __restrict__ idx, int* __restrict__ cursor,
                          int* __restrict__ tl) {
  int t = blockIdx.x * 256 + threadIdx.x;
  int pos = atomicAdd(&cursor[idx[t]], 1);
  tl[pos] = t;
}

// ---------------- fp32 -> bf16 conversion: x + wgu only ----------------
__global__ void k_cvt_xw(const float* __restrict__ x, const float* __restrict__ wgu,
                         u16* __restrict__ xb, u16* __restrict__ wgub) {
  const size_t N1 = (size_t)NTOK * DM;
  const size_t N2 = (size_t)NE * 2 * DFF * DM;
  const size_t total4 = (N1 + N2) / 4;
  for (size_t q = (size_t)blockIdx.x * 256 + threadIdx.x; q < total4;
       q += (size_t)gridDim.x * 256) {
    size_t i = q * 4;
    const float* s;
    u16* d;
    if (i < N1) { s = x + i; d = xb + i; }
    else { s = wgu + (i - N1); d = wgub + (i - N1); }
    float4 v = *(const float4*)s;
    ushort4 o;
    o.x = f2bf(v.x); o.y = f2bf(v.y); o.z = f2bf(v.z); o.w = f2bf(v.w);
    *(ushort4*)d = o;
  }
}

// ---------------- GEMM1 main: rows [0,2048), EXACTLY 1024 blocks = 4 rounds --
// r6 geometry + barrier diet + serial wd->wdb fold prologue.
__global__ __launch_bounds__(512, 2) void k_gemm1(
    const u16* __restrict__ xb, const u16* __restrict__ wgu,
    u16* __restrict__ hid, const int* __restrict__ tl,
    const int* __restrict__ offs, const int* __restrict__ counts,
    const float* __restrict__ wd, u16* __restrict__ wdb) {
  int wg = blockIdx.x;
  int tid = threadIdx.x;

  // ---- wd fp32 -> bf16 fold (1024 blocks; exactly 8 float4 per thread) ----
  {
    const size_t WD4 = (size_t)NE * DM * DFF / 4;
    for (size_t i = (size_t)wg * 512 + tid; i < WD4; i += (size_t)1024 * 512) {
      float4 v = *(const float4*)(wd + i * 4);
      ushort4 o;
      o.x = f2bf(v.x); o.y = f2bf(v.y); o.z = f2bf(v.z); o.w = f2bf(v.w);
      *(ushort4*)(wdb + i * 4) = o;
    }
  }

  int e = wg & 7;            // expert -> XCD pin
  int r = wg >> 3;           // 0..127
  int bx = r & 7;            // 0..7, fastest: consecutive blocks share by
  int by = r >> 3;           // 0..15
  int Me = counts[e];
  int m0 = bx * 256;
  if (m0 >= Me) return;
  int n0 = by * 128;
  int oe = offs[e];
  const int* tle = tl + oe;

  int lane = tid & 63;
  int wid = tid >> 6;        // 0..7
  int wm = wid >> 2;         // 0..1
  int wn = wid & 3;          // 0..3

  __shared__ u16 lds[2][2][256 * 64];  // 128 KiB

  int lr = lane >> 3;
  int swz = ((lane & 7) ^ lr) * 8;     // pre-swizzled source slot
  const u16* pA[4];
  const u16* pB[4];
#pragma unroll
  for (int j = 0; j < 4; j++) {
    int c = j * 8 + wid;               // 0..31
    int a = m0 + c * 8 + lr;
    if (a >= Me) a = Me - 1;
    pA[j] = xb + (size_t)tle[a] * DM + swz;
    int b = c * 8 + lr;                // 0..255
    int grow = ((b >> 5) & 1) * DFF + n0 + ((b >> 6) & 3) * 32 + (b & 31);
    pB[j] = wgu + ((size_t)e * 2 * DFF + grow) * DM + swz;
  }

  f32x4 acc[8][4];
#pragma unroll
  for (int m = 0; m < 8; m++)
#pragma unroll
    for (int f = 0; f < 4; f++) acc[m][f] = (f32x4){0.f, 0.f, 0.f, 0.f};

  const int r15 = lane & 15;
  const int hi4 = lane >> 4;
  const int rx = r15 & 7;

#pragma unroll
  for (int j = 0; j < 4; j++) {
    int off = (j * 8 + wid) * 1024;
    async16(pA[j], (char*)&lds[0][0][0] + off);
    async16(pB[j], (char*)&lds[0][1][0] + off);
  }
  asm volatile("s_waitcnt vmcnt(0)" ::: "memory");
  __builtin_amdgcn_s_barrier();
  __builtin_amdgcn_sched_barrier(0);

  int cur = 0;
#pragma unroll 1
  for (int t = 0; t < DM / 64; t++) {
    const char* Ab = (const char*)&lds[cur][0][0];
    const char* Bb = (const char*)&lds[cur][1][0];
    char* LA = (char*)&lds[cur ^ 1][0][0];
    char* LB = (char*)&lds[cur ^ 1][1][0];
    int k1 = (t + 1) * 64;
    bool pf = (t < DM / 64 - 1);
    bf16x8 bfr[4][2];
#pragma unroll
    for (int p = 0; p < 4; p++) {
      if (p == 0) {
#pragma unroll
        for (int f = 0; f < 4; f++)
#pragma unroll
          for (int kk = 0; kk < 2; kk++) {
            int row = wn * 64 + f * 16 + r15;
            bfr[f][kk] = *(const bf16x8*)(Bb + row * 128 + (((kk * 4 + hi4) ^ rx) * 16));
          }
      }
      bf16x8 af[2][2];
#pragma unroll
      for (int i = 0; i < 2; i++)
#pragma unroll
        for (int kk = 0; kk < 2; kk++) {
          int row = wm * 128 + (2 * p + i) * 16 + r15;
          af[i][kk] = *(const bf16x8*)(Ab + row * 128 + (((kk * 4 + hi4) ^ rx) * 16));
        }
      if (pf && p < 2) {
#pragma unroll
        for (int j = 0; j < 2; j++) {
          int jj = p * 2 + j;
          int off = (jj * 8 + wid) * 1024;
          async16(pA[jj] + k1, LA + off);
          async16(pB[jj] + k1, LB + off);
        }
      }
      __builtin_amdgcn_sched_barrier(0);
      __builtin_amdgcn_s_setprio(1);
#pragma unroll
      for (int kk = 0; kk < 2; kk++)
#pragma unroll
        for (int i = 0; i < 2; i++)
#pragma unroll
          for (int f = 0; f < 4; f++)
            acc[2 * p + i][f] = __builtin_amdgcn_mfma_f32_16x16x32_bf16(
                af[i][kk], bfr[f][kk], acc[2 * p + i][f], 0, 0, 0);
      __builtin_amdgcn_s_setprio(0);
      __builtin_amdgcn_sched_barrier(0);
    }
    asm volatile("s_waitcnt vmcnt(0)" ::: "memory");
    __builtin_amdgcn_s_barrier();
    __builtin_amdgcn_sched_barrier(0);
    cur ^= 1;
  }

  int colb = n0 + wn * 32 + r15;
#pragma unroll
  for (int m = 0; m < 8; m++) {
#pragma unroll
    for (int rr = 0; rr < 4; rr++) {
      int gm = m0 + wm * 128 + m * 16 + hi4 * 4 + rr;
      if (gm < Me) {
        size_t rowp = (size_t)(oe + gm) * DFF;
#pragma unroll
        for (int f = 0; f < 2; f++) {
          float g = acc[m][f][rr];
          float u = acc[m][f + 2][rr];
          float s = g / (1.0f + __expf(-g));
          hid[rowp + colb + f * 16] = f2bf(s * u);
        }
      }
    }
  }
}

// ---------------- GEMM1 overflow: rows [2048, 2304), BM=64 x 64 hidden cols --
// Thin quantum: 48 KiB LDS -> 3 blocks/CU. Grid 4bx x 32by x 8e = 1024 slots,
// ~130 active, each ~33 MF. B-tile 128 rows: b -> gate/up of col
// n0 + (b>>5)*16 + (b&15), gate/up flag (b>>4)&1 -> per-thread silu pairing.
__global__ __launch_bounds__(512, 2) void k_gemm1_ovf(
    const u16* __restrict__ xb, const u16* __restrict__ wgu,
    u16* __restrict__ hid, const int* __restrict__ tl,
    const int* __restrict__ offs, const int* __restrict__ counts) {
  int wg = blockIdx.x;
  int e = wg & 7;
  int r = wg >> 3;           // 0..127
  int bx = r & 3;            // 0..3
  int by = r >> 2;           // 0..31
  int Me = counts[e];
  int m0 = 2048 + bx * 64;
  if (m0 >= Me) return;
  int n0 = by * 64;
  int oe = offs[e];
  const int* tle = tl + oe;

  int tid = threadIdx.x;
  int lane = tid & 63;
  int wid = tid >> 6;        // 0..7
  int wm = wid >> 2;         // 0..1
  int wn = wid & 3;          // 0..3

  __shared__ u16 ldsA[2][64 * 64];    // 16 KiB
  __shared__ u16 ldsB[2][128 * 64];   // 32 KiB

  int lr = lane >> 3;
  int swz = ((lane & 7) ^ lr) * 8;
  const u16* pAo;
  const u16* pB[2];
  {
    int a = m0 + wid * 8 + lr;
    if (a >= Me) a = Me - 1;
    pAo = xb + (size_t)tle[a] * DM + swz;
  }
#pragma unroll
  for (int j = 0; j < 2; j++) {
    int c = j * 8 + wid;               // 0..15
    int b = c * 8 + lr;                // 0..127
    int grow = ((b >> 4) & 1) * DFF + n0 + (b >> 5) * 16 + (b & 15);
    pB[j] = wgu + ((size_t)e * 2 * DFF + grow) * DM + swz;
  }

  f32x4 acc[2][2];
#pragma unroll
  for (int m = 0; m < 2; m++)
#pragma unroll
    for (int f = 0; f < 2; f++) acc[m][f] = (f32x4){0.f, 0.f, 0.f, 0.f};

  const int r15 = lane & 15;
  const int hi4 = lane >> 4;
  const int rx = r15 & 7;

  async16(pAo, (char*)&ldsA[0][0] + wid * 1024);
#pragma unroll
  for (int j = 0; j < 2; j++)
    async16(pB[j], (char*)&ldsB[0][0] + (j * 8 + wid) * 1024);
  asm volatile("s_waitcnt vmcnt(0)" ::: "memory");
  __builtin_amdgcn_s_barrier();
  __builtin_amdgcn_sched_barrier(0);

  int cur = 0;
#pragma unroll 1
  for (int t = 0; t < DM / 64; t++) {
    const char* Ab = (const char*)&ldsA[cur][0];
    const char* Bb = (const char*)&ldsB[cur][0];
    char* LA = (char*)&ldsA[cur ^ 1][0];
    char* LB = (char*)&ldsB[cur ^ 1][0];
    int k1 = (t + 1) * 64;
    bool pf = (t < DM / 64 - 1);
    bf16x8 bfr[2][2], af[2][2];
#pragma unroll
    for (int kk = 0; kk < 2; kk++) {
#pragma unroll
      for (int f = 0; f < 2; f++) {
        int row = wn * 32 + f * 16 + r15;
        bfr[f][kk] = *(const bf16x8*)(Bb + row * 128 + (((kk * 4 + hi4) ^ rx) * 16));
      }
#pragma unroll
      for (int i = 0; i < 2; i++) {
        int arow = wm * 32 + i * 16 + r15;
        af[i][kk] = *(const bf16x8*)(Ab + arow * 128 + (((kk * 4 + hi4) ^ rx) * 16));
      }
    }
    if (pf) {
      async16(pAo + k1, LA + wid * 1024);
#pragma unroll
      for (int j = 0; j < 2; j++)
        async16(pB[j] + k1, LB + (j * 8 + wid) * 1024);
    }
    __builtin_amdgcn_sched_barrier(0);
    __builtin_amdgcn_s_setprio(1);
#pragma unroll
    for (int kk = 0; kk < 2; kk++)
#pragma unroll
      for (int i = 0; i < 2; i++)
#pragma unroll
        for (int f = 0; f < 2; f++)
          acc[i][f] = __builtin_amdgcn_mfma_f32_16x16x32_bf16(af[i][kk], bfr[f][kk], acc[i][f], 0, 0, 0);
    __builtin_amdgcn_s_setprio(0);
    __builtin_amdgcn_sched_barrier(0);
    asm volatile("s_waitcnt vmcnt(0)" ::: "memory");
    __builtin_amdgcn_s_barrier();
    __builtin_amdgcn_sched_barrier(0);
    cur ^= 1;
  }

  // fragment f=0 is gate, f=1 is up, same hidden col = n0 + wn*16 + r15
  int colh = n0 + wn * 16 + r15;
#pragma unroll
  for (int m = 0; m < 2; m++) {
#pragma unroll
    for (int rr = 0; rr < 4; rr++) {
      int gm = m0 + wm * 32 + m * 16 + hi4 * 4 + rr;
      if (gm < Me) {
        float g = acc[m][0][rr];
        float u = acc[m][1][rr];
        float s = g / (1.0f + __expf(-g));
        hid[(size_t)(oe + gm) * DFF + colh] = f2bf(s * u);
      }
    }
  }
}

// ---------------- GEMM2 main: rows [0,2048), EXACTLY 256 blocks ----
__global__ __launch_bounds__(512, 2) void k_gemm2(
    const u16* __restrict__ hid, const u16* __restrict__ wd,
    float* __restrict__ out, const int* __restrict__ tl,
    const int* __restrict__ offs, const int* __restrict__ counts) {
  int wg = blockIdx.x;
  int e = wg & 7;
  int r = wg >> 3;           // 0..31
  int bx = r & 7;            // 0..7
  int by = r >> 3;           // 0..3
  int Me = counts[e];
  int m0 = bx * 256;
  if (m0 >= Me) return;
  int n0 = by * 256;
  int oe = offs[e];
  const int* tle = tl + oe;

  int tid = threadIdx.x;
  int lane = tid & 63;
  int wid = tid >> 6;
  int wm = wid >> 2;         // 0..1
  int wn = wid & 3;          // 0..3

  __shared__ u16 lds[2][2][256 * 64];  // 128 KiB

  int lr = lane >> 3;
  int swz = ((lane & 7) ^ lr) * 8;
  const u16* pA[4];
  const u16* pB[4];
#pragma unroll
  for (int j = 0; j < 4; j++) {
    int c = j * 8 + wid;               // 0..31
    int a = m0 + c * 8 + lr;
    if (a >= Me) a = Me - 1;
    pA[j] = hid + (size_t)(oe + a) * DFF + swz;
    pB[j] = wd + ((size_t)e * DM + n0 + c * 8 + lr) * DFF + swz;
  }

  f32x4 acc[8][4];
#pragma unroll
  for (int m = 0; m < 8; m++)
#pragma unroll
    for (int f = 0; f < 4; f++) acc[m][f] = (f32x4){0.f, 0.f, 0.f, 0.f};

  const int r15 = lane & 15;
  const int hi4 = lane >> 4;
  const int rx = r15 & 7;

#pragma unroll
  for (int j = 0; j < 4; j++) {
    int off = (j * 8 + wid) * 1024;
    async16(pA[j], (char*)&lds[0][0][0] + off);
    async16(pB[j], (char*)&lds[0][1][0] + off);
  }
  asm volatile("s_waitcnt vmcnt(0)" ::: "memory");
  __builtin_amdgcn_s_barrier();
  __builtin_amdgcn_sched_barrier(0);

  int cur = 0;
#pragma unroll 1
  for (int t = 0; t < DFF / 64; t++) {
    const char* Ab = (const char*)&lds[cur][0][0];
    const char* Bb = (const char*)&lds[cur][1][0];
    char* LA = (char*)&lds[cur ^ 1][0][0];
    char* LB = (char*)&lds[cur ^ 1][1][0];
    int k1 = (t + 1) * 64;
    bool pf = (t < DFF / 64 - 1);
    bf16x8 bfr[4][2];
#pragma unroll
    for (int p = 0; p < 4; p++) {
      if (p == 0) {
#pragma unroll
        for (int f = 0; f < 4; f++)
#pragma unroll
          for (int kk = 0; kk < 2; kk++) {
            int row = wn * 64 + f * 16 + r15;
            bfr[f][kk] = *(const bf16x8*)(Bb + row * 128 + (((kk * 4 + hi4) ^ rx) * 16));
          }
      }
      bf16x8 af[2][2];
#pragma unroll
      for (int i = 0; i < 2; i++)
#pragma unroll
        for (int kk = 0; kk < 2; kk++) {
          int row = wm * 128 + (2 * p + i) * 16 + r15;
          af[i][kk] = *(const bf16x8*)(Ab + row * 128 + (((kk * 4 + hi4) ^ rx) * 16));
        }
      if (pf && p < 2) {
#pragma unroll
        for (int j = 0; j < 2; j++) {
          int jj = p * 2 + j;
          int off = (jj * 8 + wid) * 1024;
          async16(pA[jj] + k1, LA + off);
          async16(pB[jj] + k1, LB + off);
        }
      }
      __builtin_amdgcn_sched_barrier(0);
      __builtin_amdgcn_s_setprio(1);
#pragma unroll
      for (int kk = 0; kk < 2; kk++)
#pragma unroll
        for (int i = 0; i < 2; i++)
#pragma unroll
          for (int f = 0; f < 4; f++)
            acc[2 * p + i][f] = __builtin_amdgcn_mfma_f32_16x16x32_bf16(
                af[i][kk], bfr[f][kk], acc[2 * p + i][f], 0, 0, 0);
      __builtin_amdgcn_s_setprio(0);
      __builtin_amdgcn_sched_barrier(0);
    }
    asm volatile("s_waitcnt vmcnt(0)" ::: "memory");
    __builtin_amdgcn_s_barrier();
    __builtin_amdgcn_sched_barrier(0);
    cur ^= 1;
  }

  int colb = n0 + wn * 64 + r15;
#pragma unroll
  for (int m = 0; m < 8; m++) {
#pragma unroll
    for (int rr = 0; rr < 4; rr++) {
      int gm = m0 + wm * 128 + m * 16 + hi4 * 4 + rr;
      if (gm < Me) {
        int tk = tle[gm];
#pragma unroll
        for (int f = 0; f < 4; f++)
          out[(size_t)tk * DM + colb + f * 16] = acc[m][f][rr];
      }
    }
  }
}

// ---------------- GEMM2 overflow: rows [2048, 2304), BM=64 x BN=64 ----------
__global__ __launch_bounds__(512, 2) void k_gemm2_ovf(
    const u16* __restrict__ hid, const u16* __restrict__ wd,
    float* __restrict__ out, const int* __restrict__ tl,
    const int* __restrict__ offs, const int* __restrict__ counts) {
  int wg = blockIdx.x;
  int e = wg & 7;
  int r = wg >> 3;           // 0..63
  int bx = r & 3;            // 0..3
  int by = r >> 2;           // 0..15
  int Me = counts[e];
  int m0 = 2048 + bx * 64;
  if (m0 >= Me) return;
  int n0 = by * 64;
  int oe = offs[e];
  const int* tle = tl + oe;

  int tid = threadIdx.x;
  int lane = tid & 63;
  int wid = tid >> 6;        // 0..7
  int wm = wid >> 2;         // 0..1
  int wn = wid & 3;          // 0..3

  __shared__ u16 ldsA[2][64 * 64];   // 16 KiB
  __shared__ u16 ldsB[2][64 * 64];   // 16 KiB

  int lr = lane >> 3;
  int swz = ((lane & 7) ^ lr) * 8;
  const u16* pAo;
  const u16* pBo;
  {
    int a = m0 + wid * 8 + lr;
    if (a >= Me) a = Me - 1;
    pAo = hid + (size_t)(oe + a) * DFF + swz;
    pBo = wd + ((size_t)e * DM + n0 + wid * 8 + lr) * DFF + swz;
  }

  f32x4 acc[2];
#pragma unroll
  for (int m = 0; m < 2; m++) acc[m] = (f32x4){0.f, 0.f, 0.f, 0.f};

  const int r15 = lane & 15;
  const int hi4 = lane >> 4;
  const int rx = r15 & 7;

  async16(pAo, (char*)&ldsA[0][0] + wid * 1024);
  async16(pBo, (char*)&ldsB[0][0] + wid * 1024);
  asm volatile("s_waitcnt vmcnt(0)" ::: "memory");
  __builtin_amdgcn_s_barrier();
  __builtin_amdgcn_sched_barrier(0);

  int cur = 0;
#pragma unroll 1
  for (int t = 0; t < DFF / 64; t++) {
    const char* Ab = (const char*)&ldsA[cur][0];
    const char* Bb = (const char*)&ldsB[cur][0];
    char* LA = (char*)&ldsA[cur ^ 1][0];
    char* LB = (char*)&ldsB[cur ^ 1][0];
    int k1 = (t + 1) * 64;
    bool pf = (t < DFF / 64 - 1);
    bf16x8 bfr[2], af[2][2];
#pragma unroll
    for (int kk = 0; kk < 2; kk++) {
      int row = wn * 16 + r15;
      bfr[kk] = *(const bf16x8*)(Bb + row * 128 + (((kk * 4 + hi4) ^ rx) * 16));
#pragma unroll
      for (int i = 0; i < 2; i++) {
        int arow = wm * 32 + i * 16 + r15;
        af[i][kk] = *(const bf16x8*)(Ab + arow * 128 + (((kk * 4 + hi4) ^ rx) * 16));
      }
    }
    if (pf) {
      async16(pAo + k1, LA + wid * 1024);
      async16(pBo + k1, LB + wid * 1024);
    }
    __builtin_amdgcn_sched_barrier(0);
    __builtin_amdgcn_s_setprio(1);
#pragma unroll
    for (int kk = 0; kk < 2; kk++)
#pragma unroll
      for (int i = 0; i < 2; i++)
        acc[i] = __builtin_amdgcn_mfma_f32_16x16x32_bf16(af[i][kk], bfr[kk], acc[i], 0, 0, 0);
    __builtin_amdgcn_s_setprio(0);
    __builtin_amdgcn_sched_barrier(0);
    asm volatile("s_waitcnt vmcnt(0)" ::: "memory");
    __builtin_amdgcn_s_barrier();
    __builtin_amdgcn_sched_barrier(0);
    cur ^= 1;
  }

  int colb = n0 + wn * 16 + r15;
#pragma unroll
  for (int m = 0; m < 2; m++) {
#pragma unroll
    for (int rr = 0; rr < 4; rr++) {
      int gm = m0 + wm * 32 + m * 16 + hi4 * 4 + rr;
      if (gm < Me) {
        int tk = tle[gm];
        out[(size_t)tk * DM + colb] = acc[m][rr];
      }
    }
  }
}

extern "C" void kernel_launch(void* const* d_in, const int* in_sizes, int n_in,
                              void* d_out, int out_size, void* d_ws, size_t ws_size,
                              hipStream_t stream) {
  const float* x   = (const float*)d_in[0];
  const int* eidx  = (const int*)d_in[1];
  const float* wgu = (const float*)d_in[2];
  const float* wd  = (const float*)d_in[3];
  float* out = (float*)d_out;
  char* ws = (char*)d_ws;

  int* ctrl = (int*)ws;                          // counts[8], offs[8], cursor[8]
  int* toklist = (int*)(ws + 256);               // 16384 ints
  u16* xb   = (u16*)(ws + 65792);                // 32 MB
  u16* wgub = (u16*)(ws + 65792 + 33554432ull);  // 64 MB
  u16* wdb  = (u16*)(ws + 65792 + 33554432ull + 67108864ull);   // 32 MB
  u16* hid  = (u16*)(ws + 65792 + 33554432ull + 67108864ull + 33554432ull);  // 64 MB

  hipMemsetAsync(ws, 0, 256, stream);
  k_count<<<NTOK / 256, 256, 0, stream>>>(eidx, ctrl);
  k_offsets<<<1, 64, 0, stream>>>(ctrl);
  k_scatter<<<NTOK / 256, 256, 0, stream>>>(eidx, ctrl + 16, toklist);

  k_cvt_xw<<<2048, 256, 0, stream>>>(x, wgu, xb, wgub);

  // g1: main = EXACTLY 1024 blocks (4.0 rounds, rows < 2048) + thin overflow
  // (rows 2048..2303, ~130 active co-resident blocks).
  k_gemm1<<<8 * 16 * NE, 512, 0, stream>>>(xb, wgub, hid, toklist, ctrl + 8, ctrl, wd, wdb);
  k_gemm1_ovf<<<4 * 32 * NE, 512, 0, stream>>>(xb, wgub, hid, toklist, ctrl + 8, ctrl);
  // g2: main = EXACTLY 256 blocks (1 round) + thin overflow.
  k_gemm2<<<8 * 4 * NE, 512, 0, stream>>>(hid, wdb, out, toklist, ctrl + 8, ctrl);
  k_gemm2_ovf<<<4 * 16 * NE, 512, 0, stream>>>(hid, wdb, out, toklist, ctrl + 8, ctrl);
}

// Round 20
// 446.308 us; speedup vs baseline: 1.2337x; 1.0085x over previous
//
#include <hip/hip_runtime.h>

#define NTOK 16384
#define DM 1024
#define DFF 2048
#define NE 8

typedef unsigned short u16;
typedef __attribute__((ext_vector_type(8))) short bf16x8;
typedef __attribute__((ext_vector_type(4))) float f32x4;

__device__ __forceinline__ u16 f2bf(float f) {
  unsigned u = __float_as_uint(f);
  u += 0x7fff + ((u >> 16) & 1);
  return (u16)(u >> 16);
}

__device__ __forceinline__ void async16(const void* g, void* l) {
  __builtin_amdgcn_global_load_lds(
      (const __attribute__((address_space(1))) unsigned int*)g,
      (__attribute__((address_space(3))) unsigned int*)l, 16, 0, 0);
}

// ---------------- routing ----------------
__global__ void k_count(const int* __restrict__ idx, int* __restrict__ counts) {
  int t = blockIdx.x * 256 + threadIdx.x;
  atomicAdd(&counts[idx[t]], 1);
}

__global__ void k_offsets(int* __restrict__ c) {
  if (threadIdx.x == 0) {
    int acc = 0;
    for (int e = 0; e < NE; e++) { c[8 + e] = acc; c[16 + e] = acc; acc += c[e]; }
  }
}

__global__ void k_scatter(const int* __restrict__ idx, int* __restrict__ cursor,
                          int* __restrict__ tl) {
  int t = blockIdx.x * 256 + threadIdx.x;
  int pos = atomicAdd(&cursor[idx[t]], 1);
  tl[pos] = t;
}

// ---------------- fp32 -> bf16 conversion: x + wgu only ----------------
__global__ void k_cvt_xw(const float* __restrict__ x, const float* __restrict__ wgu,
                         u16* __restrict__ xb, u16* __restrict__ wgub) {
  const size_t N1 = (size_t)NTOK * DM;
  const size_t N2 = (size_t)NE * 2 * DFF * DM;
  const size_t total4 = (N1 + N2) / 4;
  for (size_t q = (size_t)blockIdx.x * 256 + threadIdx.x; q < total4;
       q += (size_t)gridDim.x * 256) {
    size_t i = q * 4;
    const float* s;
    u16* d;
    if (i < N1) { s = x + i; d = xb + i; }
    else { s = wgu + (i - N1); d = wgub + (i - N1); }
    float4 v = *(const float4*)s;
    ushort4 o;
    o.x = f2bf(v.x); o.y = f2bf(v.y); o.z = f2bf(v.z); o.w = f2bf(v.w);
    *(ushort4*)d = o;
  }
}

// ---------------- GEMM1 main: rows [0,2048), EXACTLY 1024 blocks = 4 rounds --
__global__ __launch_bounds__(512, 2) void k_gemm1(
    const u16* __restrict__ xb, const u16* __restrict__ wgu,
    u16* __restrict__ hid, const int* __restrict__ tl,
    const int* __restrict__ offs, const int* __restrict__ counts,
    const float* __restrict__ wd, u16* __restrict__ wdb) {
  int wg = blockIdx.x;
  int tid = threadIdx.x;

  // ---- wd fp32 -> bf16 fold (1024 blocks; exactly 8 float4 per thread) ----
  {
    const size_t WD4 = (size_t)NE * DM * DFF / 4;
    for (size_t i = (size_t)wg * 512 + tid; i < WD4; i += (size_t)1024 * 512) {
      float4 v = *(const float4*)(wd + i * 4);
      ushort4 o;
      o.x = f2bf(v.x); o.y = f2bf(v.y); o.z = f2bf(v.z); o.w = f2bf(v.w);
      *(ushort4*)(wdb + i * 4) = o;
    }
  }

  int e = wg & 7;            // expert -> XCD pin
  int r = wg >> 3;           // 0..127
  int bx = r & 7;            // 0..7
  int by = r >> 3;           // 0..15
  int Me = counts[e];
  int m0 = bx * 256;
  if (m0 >= Me) return;
  int n0 = by * 128;
  int oe = offs[e];
  const int* tle = tl + oe;

  int lane = tid & 63;
  int wid = tid >> 6;        // 0..7
  int wm = wid >> 2;         // 0..1
  int wn = wid & 3;          // 0..3

  __shared__ u16 lds[2][2][256 * 64];  // 128 KiB

  int lr = lane >> 3;
  int swz = ((lane & 7) ^ lr) * 8;     // pre-swizzled source slot
  const u16* pA[4];
  const u16* pB[4];
#pragma unroll
  for (int j = 0; j < 4; j++) {
    int c = j * 8 + wid;               // 0..31
    int a = m0 + c * 8 + lr;
    if (a >= Me) a = Me - 1;
    pA[j] = xb + (size_t)tle[a] * DM + swz;
    int b = c * 8 + lr;                // 0..255
    int grow = ((b >> 5) & 1) * DFF + n0 + ((b >> 6) & 3) * 32 + (b & 31);
    pB[j] = wgu + ((size_t)e * 2 * DFF + grow) * DM + swz;
  }

  f32x4 acc[8][4];
#pragma unroll
  for (int m = 0; m < 8; m++)
#pragma unroll
    for (int f = 0; f < 4; f++) acc[m][f] = (f32x4){0.f, 0.f, 0.f, 0.f};

  const int r15 = lane & 15;
  const int hi4 = lane >> 4;
  const int rx = r15 & 7;

#pragma unroll
  for (int j = 0; j < 4; j++) {
    int off = (j * 8 + wid) * 1024;
    async16(pA[j], (char*)&lds[0][0][0] + off);
    async16(pB[j], (char*)&lds[0][1][0] + off);
  }
  asm volatile("s_waitcnt vmcnt(0)" ::: "memory");
  __builtin_amdgcn_s_barrier();
  __builtin_amdgcn_sched_barrier(0);

  int cur = 0;
#pragma unroll 1
  for (int t = 0; t < DM / 64; t++) {
    const char* Ab = (const char*)&lds[cur][0][0];
    const char* Bb = (const char*)&lds[cur][1][0];
    char* LA = (char*)&lds[cur ^ 1][0][0];
    char* LB = (char*)&lds[cur ^ 1][1][0];
    int k1 = (t + 1) * 64;
    bool pf = (t < DM / 64 - 1);
    bf16x8 bfr[4][2];
#pragma unroll
    for (int p = 0; p < 4; p++) {
      if (p == 0) {
#pragma unroll
        for (int f = 0; f < 4; f++)
#pragma unroll
          for (int kk = 0; kk < 2; kk++) {
            int row = wn * 64 + f * 16 + r15;
            bfr[f][kk] = *(const bf16x8*)(Bb + row * 128 + (((kk * 4 + hi4) ^ rx) * 16));
          }
      }
      bf16x8 af[2][2];
#pragma unroll
      for (int i = 0; i < 2; i++)
#pragma unroll
        for (int kk = 0; kk < 2; kk++) {
          int row = wm * 128 + (2 * p + i) * 16 + r15;
          af[i][kk] = *(const bf16x8*)(Ab + row * 128 + (((kk * 4 + hi4) ^ rx) * 16));
        }
      if (pf && p < 2) {
#pragma unroll
        for (int j = 0; j < 2; j++) {
          int jj = p * 2 + j;
          int off = (jj * 8 + wid) * 1024;
          async16(pA[jj] + k1, LA + off);
          async16(pB[jj] + k1, LB + off);
        }
      }
      __builtin_amdgcn_sched_barrier(0);
      __builtin_amdgcn_s_setprio(1);
#pragma unroll
      for (int kk = 0; kk < 2; kk++)
#pragma unroll
        for (int i = 0; i < 2; i++)
#pragma unroll
          for (int f = 0; f < 4; f++)
            acc[2 * p + i][f] = __builtin_amdgcn_mfma_f32_16x16x32_bf16(
                af[i][kk], bfr[f][kk], acc[2 * p + i][f], 0, 0, 0);
      __builtin_amdgcn_s_setprio(0);
      __builtin_amdgcn_sched_barrier(0);
    }
    asm volatile("s_waitcnt vmcnt(0)" ::: "memory");
    __builtin_amdgcn_s_barrier();
    __builtin_amdgcn_sched_barrier(0);
    cur ^= 1;
  }

  int colb = n0 + wn * 32 + r15;
#pragma unroll
  for (int m = 0; m < 8; m++) {
#pragma unroll
    for (int rr = 0; rr < 4; rr++) {
      int gm = m0 + wm * 128 + m * 16 + hi4 * 4 + rr;
      if (gm < Me) {
        size_t rowp = (size_t)(oe + gm) * DFF;
#pragma unroll
        for (int f = 0; f < 2; f++) {
          float g = acc[m][f][rr];
          float u = acc[m][f + 2][rr];
          float s = g / (1.0f + __expf(-g));
          hid[rowp + colb + f * 16] = f2bf(s * u);
        }
      }
    }
  }
}

// ---------------- GEMM1 overflow: rows [2048, 2304), BM=64 x 64 hidden cols --
// LATENCY FIX: triple buffer, prefetch distance 2, counted vmcnt(3) -- the
// t+1 loads were issued a full tile earlier, so the boundary wait is ~free.
__global__ __launch_bounds__(512, 2) void k_gemm1_ovf(
    const u16* __restrict__ xb, const u16* __restrict__ wgu,
    u16* __restrict__ hid, const int* __restrict__ tl,
    const int* __restrict__ offs, const int* __restrict__ counts) {
  int wg = blockIdx.x;
  int e = wg & 7;
  int r = wg >> 3;           // 0..127
  int bx = r & 3;            // 0..3
  int by = r >> 2;           // 0..31
  int Me = counts[e];
  int m0 = 2048 + bx * 64;
  if (m0 >= Me) return;
  int n0 = by * 64;
  int oe = offs[e];
  const int* tle = tl + oe;

  int tid = threadIdx.x;
  int lane = tid & 63;
  int wid = tid >> 6;        // 0..7
  int wm = wid >> 2;         // 0..1
  int wn = wid & 3;          // 0..3

  __shared__ u16 ldsA[3][64 * 64];    // 24 KiB
  __shared__ u16 ldsB[3][128 * 64];   // 48 KiB

  int lr = lane >> 3;
  int swz = ((lane & 7) ^ lr) * 8;
  const u16* pAo;
  const u16* pB[2];
  {
    int a = m0 + wid * 8 + lr;
    if (a >= Me) a = Me - 1;
    pAo = xb + (size_t)tle[a] * DM + swz;
  }
#pragma unroll
  for (int j = 0; j < 2; j++) {
    int c = j * 8 + wid;               // 0..15
    int b = c * 8 + lr;                // 0..127
    int grow = ((b >> 4) & 1) * DFF + n0 + (b >> 5) * 16 + (b & 15);
    pB[j] = wgu + ((size_t)e * 2 * DFF + grow) * DM + swz;
  }

  f32x4 acc[2][2];
#pragma unroll
  for (int m = 0; m < 2; m++)
#pragma unroll
    for (int f = 0; f < 2; f++) acc[m][f] = (f32x4){0.f, 0.f, 0.f, 0.f};

  const int r15 = lane & 15;
  const int hi4 = lane >> 4;
  const int rx = r15 & 7;

  char* A0 = (char*)&ldsA[0][0]; char* A1 = (char*)&ldsA[1][0]; char* A2 = (char*)&ldsA[2][0];
  char* B0 = (char*)&ldsB[0][0]; char* B1 = (char*)&ldsB[1][0]; char* B2 = (char*)&ldsB[2][0];
  const int NT = DM / 64;    // 16

  // prologue: stage tiles 0 and 1 (3 VMEM ops per thread per tile)
  async16(pAo, A0 + wid * 1024);
#pragma unroll
  for (int j = 0; j < 2; j++) async16(pB[j], B0 + (j * 8 + wid) * 1024);
  async16(pAo + 64, A1 + wid * 1024);
#pragma unroll
  for (int j = 0; j < 2; j++) async16(pB[j] + 64, B1 + (j * 8 + wid) * 1024);
  asm volatile("s_waitcnt vmcnt(3)" ::: "memory");  // tile 0 landed
  __builtin_amdgcn_s_barrier();
  __builtin_amdgcn_sched_barrier(0);

#pragma unroll 1
  for (int t = 0; t < NT; t++) {
    int k2 = (t + 2) * 64;
    bool deep = (t + 2 < NT);
    bf16x8 bfr[2][2], af[2][2];
#pragma unroll
    for (int kk = 0; kk < 2; kk++) {
#pragma unroll
      for (int f = 0; f < 2; f++) {
        int row = wn * 32 + f * 16 + r15;
        bfr[f][kk] = *(const bf16x8*)(B0 + row * 128 + (((kk * 4 + hi4) ^ rx) * 16));
      }
#pragma unroll
      for (int i = 0; i < 2; i++) {
        int arow = wm * 32 + i * 16 + r15;
        af[i][kk] = *(const bf16x8*)(A0 + arow * 128 + (((kk * 4 + hi4) ^ rx) * 16));
      }
    }
    if (deep) {
      async16(pAo + k2, A2 + wid * 1024);
#pragma unroll
      for (int j = 0; j < 2; j++) async16(pB[j] + k2, B2 + (j * 8 + wid) * 1024);
    }
    __builtin_amdgcn_sched_barrier(0);
    __builtin_amdgcn_s_setprio(1);
#pragma unroll
    for (int kk = 0; kk < 2; kk++)
#pragma unroll
      for (int i = 0; i < 2; i++)
#pragma unroll
        for (int f = 0; f < 2; f++)
          acc[i][f] = __builtin_amdgcn_mfma_f32_16x16x32_bf16(af[i][kk], bfr[f][kk], acc[i][f], 0, 0, 0);
    __builtin_amdgcn_s_setprio(0);
    __builtin_amdgcn_sched_barrier(0);
    if (deep) { asm volatile("s_waitcnt vmcnt(3)" ::: "memory"); }  // t+1 landed
    else      { asm volatile("s_waitcnt vmcnt(0)" ::: "memory"); }
    __builtin_amdgcn_s_barrier();
    __builtin_amdgcn_sched_barrier(0);
    char* tA = A0; A0 = A1; A1 = A2; A2 = tA;
    char* tB = B0; B0 = B1; B1 = B2; B2 = tB;
  }

  int colh = n0 + wn * 16 + r15;
#pragma unroll
  for (int m = 0; m < 2; m++) {
#pragma unroll
    for (int rr = 0; rr < 4; rr++) {
      int gm = m0 + wm * 32 + m * 16 + hi4 * 4 + rr;
      if (gm < Me) {
        float g = acc[m][0][rr];
        float u = acc[m][1][rr];
        float s = g / (1.0f + __expf(-g));
        hid[(size_t)(oe + gm) * DFF + colh] = f2bf(s * u);
      }
    }
  }
}

// ---------------- GEMM2 main: rows [0,2048), EXACTLY 256 blocks ----
__global__ __launch_bounds__(512, 2) void k_gemm2(
    const u16* __restrict__ hid, const u16* __restrict__ wd,
    float* __restrict__ out, const int* __restrict__ tl,
    const int* __restrict__ offs, const int* __restrict__ counts) {
  int wg = blockIdx.x;
  int e = wg & 7;
  int r = wg >> 3;           // 0..31
  int bx = r & 7;            // 0..7
  int by = r >> 3;           // 0..3
  int Me = counts[e];
  int m0 = bx * 256;
  if (m0 >= Me) return;
  int n0 = by * 256;
  int oe = offs[e];
  const int* tle = tl + oe;

  int tid = threadIdx.x;
  int lane = tid & 63;
  int wid = tid >> 6;
  int wm = wid >> 2;         // 0..1
  int wn = wid & 3;          // 0..3

  __shared__ u16 lds[2][2][256 * 64];  // 128 KiB

  int lr = lane >> 3;
  int swz = ((lane & 7) ^ lr) * 8;
  const u16* pA[4];
  const u16* pB[4];
#pragma unroll
  for (int j = 0; j < 4; j++) {
    int c = j * 8 + wid;               // 0..31
    int a = m0 + c * 8 + lr;
    if (a >= Me) a = Me - 1;
    pA[j] = hid + (size_t)(oe + a) * DFF + swz;
    pB[j] = wd + ((size_t)e * DM + n0 + c * 8 + lr) * DFF + swz;
  }

  f32x4 acc[8][4];
#pragma unroll
  for (int m = 0; m < 8; m++)
#pragma unroll
    for (int f = 0; f < 4; f++) acc[m][f] = (f32x4){0.f, 0.f, 0.f, 0.f};

  const int r15 = lane & 15;
  const int hi4 = lane >> 4;
  const int rx = r15 & 7;

#pragma unroll
  for (int j = 0; j < 4; j++) {
    int off = (j * 8 + wid) * 1024;
    async16(pA[j], (char*)&lds[0][0][0] + off);
    async16(pB[j], (char*)&lds[0][1][0] + off);
  }
  asm volatile("s_waitcnt vmcnt(0)" ::: "memory");
  __builtin_amdgcn_s_barrier();
  __builtin_amdgcn_sched_barrier(0);

  int cur = 0;
#pragma unroll 1
  for (int t = 0; t < DFF / 64; t++) {
    const char* Ab = (const char*)&lds[cur][0][0];
    const char* Bb = (const char*)&lds[cur][1][0];
    char* LA = (char*)&lds[cur ^ 1][0][0];
    char* LB = (char*)&lds[cur ^ 1][1][0];
    int k1 = (t + 1) * 64;
    bool pf = (t < DFF / 64 - 1);
    bf16x8 bfr[4][2];
#pragma unroll
    for (int p = 0; p < 4; p++) {
      if (p == 0) {
#pragma unroll
        for (int f = 0; f < 4; f++)
#pragma unroll
          for (int kk = 0; kk < 2; kk++) {
            int row = wn * 64 + f * 16 + r15;
            bfr[f][kk] = *(const bf16x8*)(Bb + row * 128 + (((kk * 4 + hi4) ^ rx) * 16));
          }
      }
      bf16x8 af[2][2];
#pragma unroll
      for (int i = 0; i < 2; i++)
#pragma unroll
        for (int kk = 0; kk < 2; kk++) {
          int row = wm * 128 + (2 * p + i) * 16 + r15;
          af[i][kk] = *(const bf16x8*)(Ab + row * 128 + (((kk * 4 + hi4) ^ rx) * 16));
        }
      if (pf && p < 2) {
#pragma unroll
        for (int j = 0; j < 2; j++) {
          int jj = p * 2 + j;
          int off = (jj * 8 + wid) * 1024;
          async16(pA[jj] + k1, LA + off);
          async16(pB[jj] + k1, LB + off);
        }
      }
      __builtin_amdgcn_sched_barrier(0);
      __builtin_amdgcn_s_setprio(1);
#pragma unroll
      for (int kk = 0; kk < 2; kk++)
#pragma unroll
        for (int i = 0; i < 2; i++)
#pragma unroll
          for (int f = 0; f < 4; f++)
            acc[2 * p + i][f] = __builtin_amdgcn_mfma_f32_16x16x32_bf16(
                af[i][kk], bfr[f][kk], acc[2 * p + i][f], 0, 0, 0);
      __builtin_amdgcn_s_setprio(0);
      __builtin_amdgcn_sched_barrier(0);
    }
    asm volatile("s_waitcnt vmcnt(0)" ::: "memory");
    __builtin_amdgcn_s_barrier();
    __builtin_amdgcn_sched_barrier(0);
    cur ^= 1;
  }

  int colb = n0 + wn * 64 + r15;
#pragma unroll
  for (int m = 0; m < 8; m++) {
#pragma unroll
    for (int rr = 0; rr < 4; rr++) {
      int gm = m0 + wm * 128 + m * 16 + hi4 * 4 + rr;
      if (gm < Me) {
        int tk = tle[gm];
#pragma unroll
        for (int f = 0; f < 4; f++)
          out[(size_t)tk * DM + colb + f * 16] = acc[m][f][rr];
      }
    }
  }
}

// ---------------- GEMM2 overflow: rows [2048, 2304), BM=64 x BN=64 ----------
// Triple buffer, prefetch distance 2, counted vmcnt(2).
__global__ __launch_bounds__(512, 2) void k_gemm2_ovf(
    const u16* __restrict__ hid, const u16* __restrict__ wd,
    float* __restrict__ out, const int* __restrict__ tl,
    const int* __restrict__ offs, const int* __restrict__ counts) {
  int wg = blockIdx.x;
  int e = wg & 7;
  int r = wg >> 3;           // 0..63
  int bx = r & 3;            // 0..3
  int by = r >> 2;           // 0..15
  int Me = counts[e];
  int m0 = 2048 + bx * 64;
  if (m0 >= Me) return;
  int n0 = by * 64;
  int oe = offs[e];
  const int* tle = tl + oe;

  int tid = threadIdx.x;
  int lane = tid & 63;
  int wid = tid >> 6;        // 0..7
  int wm = wid >> 2;         // 0..1
  int wn = wid & 3;          // 0..3

  __shared__ u16 ldsA[3][64 * 64];   // 24 KiB
  __shared__ u16 ldsB[3][64 * 64];   // 24 KiB

  int lr = lane >> 3;
  int swz = ((lane & 7) ^ lr) * 8;
  const u16* pAo;
  const u16* pBo;
  {
    int a = m0 + wid * 8 + lr;
    if (a >= Me) a = Me - 1;
    pAo = hid + (size_t)(oe + a) * DFF + swz;
    pBo = wd + ((size_t)e * DM + n0 + wid * 8 + lr) * DFF + swz;
  }

  f32x4 acc[2];
#pragma unroll
  for (int m = 0; m < 2; m++) acc[m] = (f32x4){0.f, 0.f, 0.f, 0.f};

  const int r15 = lane & 15;
  const int hi4 = lane >> 4;
  const int rx = r15 & 7;

  char* A0 = (char*)&ldsA[0][0]; char* A1 = (char*)&ldsA[1][0]; char* A2 = (char*)&ldsA[2][0];
  char* B0 = (char*)&ldsB[0][0]; char* B1 = (char*)&ldsB[1][0]; char* B2 = (char*)&ldsB[2][0];
  const int NT = DFF / 64;   // 32

  // prologue: stage tiles 0 and 1 (2 VMEM ops per thread per tile)
  async16(pAo, A0 + wid * 1024);
  async16(pBo, B0 + wid * 1024);
  async16(pAo + 64, A1 + wid * 1024);
  async16(pBo + 64, B1 + wid * 1024);
  asm volatile("s_waitcnt vmcnt(2)" ::: "memory");  // tile 0 landed
  __builtin_amdgcn_s_barrier();
  __builtin_amdgcn_sched_barrier(0);

#pragma unroll 1
  for (int t = 0; t < NT; t++) {
    int k2 = (t + 2) * 64;
    bool deep = (t + 2 < NT);
    bf16x8 bfr[2], af[2][2];
#pragma unroll
    for (int kk = 0; kk < 2; kk++) {
      int row = wn * 16 + r15;
      bfr[kk] = *(const bf16x8*)(B0 + row * 128 + (((kk * 4 + hi4) ^ rx) * 16));
#pragma unroll
      for (int i = 0; i < 2; i++) {
        int arow = wm * 32 + i * 16 + r15;
        af[i][kk] = *(const bf16x8*)(A0 + arow * 128 + (((kk * 4 + hi4) ^ rx) * 16));
      }
    }
    if (deep) {
      async16(pAo + k2, A2 + wid * 1024);
      async16(pBo + k2, B2 + wid * 1024);
    }
    __builtin_amdgcn_sched_barrier(0);
    __builtin_amdgcn_s_setprio(1);
#pragma unroll
    for (int kk = 0; kk < 2; kk++)
#pragma unroll
      for (int i = 0; i < 2; i++)
        acc[i] = __builtin_amdgcn_mfma_f32_16x16x32_bf16(af[i][kk], bfr[kk], acc[i], 0, 0, 0);
    __builtin_amdgcn_s_setprio(0);
    __builtin_amdgcn_sched_barrier(0);
    if (deep) { asm volatile("s_waitcnt vmcnt(2)" ::: "memory"); }
    else      { asm volatile("s_waitcnt vmcnt(0)" ::: "memory"); }
    __builtin_amdgcn_s_barrier();
    __builtin_amdgcn_sched_barrier(0);
    char* tA = A0; A0 = A1; A1 = A2; A2 = tA;
    char* tB = B0; B0 = B1; B1 = B2; B2 = tB;
  }

  int colb = n0 + wn * 16 + r15;
#pragma unroll
  for (int m = 0; m < 2; m++) {
#pragma unroll
    for (int rr = 0; rr < 4; rr++) {
      int gm = m0 + wm * 32 + m * 16 + hi4 * 4 + rr;
      if (gm < Me) {
        int tk = tle[gm];
        out[(size_t)tk * DM + colb] = acc[m][rr];
      }
    }
  }
}

extern "C" void kernel_launch(void* const* d_in, const int* in_sizes, int n_in,
                              void* d_out, int out_size, void* d_ws, size_t ws_size,
                              hipStream_t stream) {
  const float* x   = (const float*)d_in[0];
  const int* eidx  = (const int*)d_in[1];
  const float* wgu = (const float*)d_in[2];
  const float* wd  = (const float*)d_in[3];
  float* out = (float*)d_out;
  char* ws = (char*)d_ws;

  int* ctrl = (int*)ws;                          // counts[8], offs[8], cursor[8]
  int* toklist = (int*)(ws + 256);               // 16384 ints
  u16* xb   = (u16*)(ws + 65792);                // 32 MB
  u16* wgub = (u16*)(ws + 65792 + 33554432ull);  // 64 MB
  u16* wdb  = (u16*)(ws + 65792 + 33554432ull + 67108864ull);   // 32 MB
  u16* hid  = (u16*)(ws + 65792 + 33554432ull + 67108864ull + 33554432ull);  // 64 MB

  hipMemsetAsync(ws, 0, 256, stream);
  k_count<<<NTOK / 256, 256, 0, stream>>>(eidx, ctrl);
  k_offsets<<<1, 64, 0, stream>>>(ctrl);
  k_scatter<<<NTOK / 256, 256, 0, stream>>>(eidx, ctrl + 16, toklist);

  k_cvt_xw<<<2048, 256, 0, stream>>>(x, wgu, xb, wgub);

  // g1: main = EXACTLY 1024 blocks (4.0 rounds) + pipelined thin overflow.
  k_gemm1<<<8 * 16 * NE, 512, 0, stream>>>(xb, wgub, hid, toklist, ctrl + 8, ctrl, wd, wdb);
  k_gemm1_ovf<<<4 * 32 * NE, 512, 0, stream>>>(xb, wgub, hid, toklist, ctrl + 8, ctrl);
  // g2: main = EXACTLY 256 blocks (1 round) + pipelined thin overflow.
  k_gemm2<<<8 * 4 * NE, 512, 0, stream>>>(hid, wdb, out, toklist, ctrl + 8, ctrl);
  k_gemm2_ovf<<<4 * 16 * NE, 512, 0, stream>>>(hid, wdb, out, toklist, ctrl + 8, ctrl);
}